// Round 1
// baseline (2316.286 us; speedup 1.0000x reference)
//
#include <hip/hip_runtime.h>
#include <hip/hip_bf16.h>
#include <math.h>

#define BB   2
#define SS   2048
#define HIDN 2048
#define HH   16
#define HKVV 4
#define DD   128
#define NCH  32   // S/CHUNK
#define CHK  64
#define NBLK 32   // S/WIN

// ---------------- fp32 tiled GEMM: C = A * Bt^T (+bias) -------------------
// A: M x K (amode 0: row-major; amode 1: head-strided read from (B,H,S,D))
// Bt: N x K row-major (weights are (out, in) -> K-contiguous)
// store: mode 0 plain C[m*N+n]; mode 1 head store into (B,NH,S,D)
__global__ __launch_bounds__(256) void gemm_bt_k(
    const float* __restrict__ A, const float* __restrict__ Bt,
    const float* __restrict__ bias, float* __restrict__ C,
    int M, int N, int K, int mode, int NH, int amode)
{
  __shared__ float As[16][68];
  __shared__ float Bs[16][68];
  int bm = blockIdx.y * 64, bn = blockIdx.x * 64;
  int tid = threadIdx.x;
  float acc[4][4] = {};
  for (int k0 = 0; k0 < K; k0 += 16) {
    for (int t = tid; t < 64 * 16; t += 256) {
      int i = t >> 4, kk = t & 15;
      int m = bm + i, kg = k0 + kk;
      float av;
      if (amode == 0) {
        av = A[(size_t)m * K + kg];
      } else {
        int b = m >> 11, s = m & 2047;
        int hh = kg >> 7, d = kg & 127;
        av = A[(size_t)((b * HH + hh) * SS + s) * DD + d];
      }
      As[kk][i] = av;
      Bs[kk][i] = Bt[(size_t)(bn + i) * K + kg];
    }
    __syncthreads();
    int tr = tid >> 4, tc = tid & 15;
    #pragma unroll
    for (int kk = 0; kk < 16; ++kk) {
      float a0[4], b0[4];
      #pragma unroll
      for (int u = 0; u < 4; u++) a0[u] = As[kk][tr * 4 + u];
      #pragma unroll
      for (int u = 0; u < 4; u++) b0[u] = Bs[kk][tc * 4 + u];
      #pragma unroll
      for (int u = 0; u < 4; u++)
        #pragma unroll
        for (int w = 0; w < 4; w++) acc[u][w] += a0[u] * b0[w];
    }
    __syncthreads();
  }
  int tr = tid >> 4, tc = tid & 15;
  for (int u = 0; u < 4; u++) {
    int m = bm + tr * 4 + u;
    int b = m >> 11, s = m & 2047;
    for (int w = 0; w < 4; w++) {
      int n = bn + tc * 4 + w;
      float val = acc[u][w] + (bias ? bias[n] : 0.0f);
      if (mode == 0) {
        C[(size_t)m * N + n] = val;
      } else {
        int hh = n >> 7, d = n & 127;
        C[(size_t)((b * NH + hh) * SS + s) * DD + d] = val;
      }
    }
  }
}

// ---------------- RoPE cos/sin table: (S x 64) ----------------------------
__global__ void rope_tab_k(const int* __restrict__ pos, float* __restrict__ ct,
                           float* __restrict__ st)
{
  int id = blockIdx.x * 256 + threadIdx.x;
  if (id >= SS * 64) return;
  int s = id >> 6, i = id & 63;
  double inv = pow(1.0e6, -(double)(2 * i) / 128.0);
  double ang = (double)pos[s] * inv;
  ct[id] = (float)cos(ang);
  st[id] = (float)sin(ang);
}

__device__ __forceinline__ float logsigf(float x)
{
  return (x >= 0.f) ? -log1pf(expf(-x)) : x - log1pf(expf(x));
}

// ---------------- prep q: softmax (in place) + rope -> sq -----------------
__global__ __launch_bounds__(256) void prep_q_k(float* __restrict__ q,
    float* __restrict__ sq, const float* __restrict__ ct, const float* __restrict__ st)
{
  int row = blockIdx.x * 4 + (threadIdx.x >> 6); // (b*H+h)*S + s
  int lane = threadIdx.x & 63;
  size_t base = (size_t)row * 128;
  int s = row & (SS - 1);
  float x0 = q[base + lane], x1 = q[base + 64 + lane];
  float m = fmaxf(x0, x1);
  for (int o = 32; o > 0; o >>= 1) m = fmaxf(m, __shfl_xor(m, o));
  float e0 = expf(x0 - m), e1 = expf(x1 - m);
  float sum = e0 + e1;
  for (int o = 32; o > 0; o >>= 1) sum += __shfl_xor(sum, o);
  float inv = 1.0f / sum;
  q[base + lane] = e0 * inv;
  q[base + 64 + lane] = e1 * inv;
  float c = ct[s * 64 + lane], sn = st[s * 64 + lane];
  sq[base + lane]      = x0 * c - x1 * sn;
  sq[base + 64 + lane] = x1 * c + x0 * sn;
}

// ---------------- prep k: softmax (in place) + gate + rope ----------------
__global__ __launch_bounds__(256) void prep_k_k(float* __restrict__ k,
    float* __restrict__ sk, float* __restrict__ g,
    const float* __restrict__ ct, const float* __restrict__ st)
{
  int row = blockIdx.x * 4 + (threadIdx.x >> 6); // (b*HKV+kv)*S + s
  int lane = threadIdx.x & 63;
  size_t base = (size_t)row * 128;
  int s = row & (SS - 1);
  float x0 = k[base + lane], x1 = k[base + 64 + lane];
  float m = fmaxf(x0, x1);
  for (int o = 32; o > 0; o >>= 1) m = fmaxf(m, __shfl_xor(m, o));
  float e0 = expf(x0 - m), e1 = expf(x1 - m);
  float sum = e0 + e1;
  for (int o = 32; o > 0; o >>= 1) sum += __shfl_xor(sum, o);
  float inv = 1.0f / sum;
  k[base + lane] = e0 * inv;
  k[base + 64 + lane] = e1 * inv;
  g[base + lane]      = logsigf(x0) * (1.0f / 16.0f);
  g[base + 64 + lane] = logsigf(x1) * (1.0f / 16.0f);
  float c = ct[s * 64 + lane], sn = st[s * 64 + lane];
  sk[base + lane]      = x0 * c - x1 * sn;
  sk[base + 64 + lane] = x1 * c + x0 * sn;
}

// ---------------- GLA pass A: per (b,kv,chunk): Gc cumsum + Tc ------------
__global__ __launch_bounds__(256) void gla_passA_k(
    const float* __restrict__ ks, const float* __restrict__ v,
    const float* __restrict__ g, float* __restrict__ Gc, float* __restrict__ Tc)
{
  int bx = blockIdx.x;             // bkvh*NCH + c
  int c = bx & 31;
  int bkvh = bx >> 5;
  __shared__ float Gs[64][128];
  __shared__ float Kg[64][128];
  __shared__ float Vs[64][128];
  size_t rowbase = ((size_t)bkvh * SS + c * 64) * 128;
  int tid = threadIdx.x;
  for (int e = tid; e < 64 * 128; e += 256) {
    int j = e >> 7, d = e & 127;
    Gs[j][d] = g[rowbase + e];
    Vs[j][d] = v[rowbase + e];
  }
  __syncthreads();
  if (tid < 128) {
    float run = 0.f;
    for (int j = 0; j < 64; j++) { run += Gs[j][tid]; Gs[j][tid] = run; }
  }
  __syncthreads();
  for (int e = tid; e < 64 * 128; e += 256) {
    int j = e >> 7, d = e & 127;
    float gc = Gs[j][d];
    Gc[rowbase + e] = gc;
    float gl = Gs[63][d];
    Kg[j][d] = ks[rowbase + e] * expf(gl - gc);
  }
  __syncthreads();
  int vcol = tid & 127, kgrp = tid >> 7;
  float acc[64];
  #pragma unroll
  for (int u = 0; u < 64; u++) acc[u] = 0.f;
  for (int j = 0; j < 64; j++) {
    float vv = Vs[j][vcol];
    #pragma unroll
    for (int u = 0; u < 64; u++) acc[u] += Kg[j][kgrp * 64 + u] * vv;
  }
  size_t tbase = (size_t)bx * 16384;
  for (int u = 0; u < 64; u++)
    Tc[tbase + (size_t)(kgrp * 64 + u) * 128 + vcol] = acc[u];
}

// ---------------- GLA pass B: parallel per-(k,v) scan over chunks ---------
__global__ __launch_bounds__(256) void gla_passB_k(
    const float* __restrict__ Tc, const float* __restrict__ Gc,
    float* __restrict__ hst)
{
  int id = blockIdx.x * 256 + threadIdx.x; // B*HKV*D*D
  int bkvh = id >> 14;
  int kv = id & 16383;
  int kk = kv >> 7;
  float h = 0.f;
  for (int c = 0; c < NCH; ++c) {
    size_t cb = ((size_t)(bkvh * NCH + c) << 14);
    hst[cb + kv] = h;
    float gl = Gc[((size_t)bkvh * SS + c * 64 + 63) * 128 + kk];
    h = h * expf(gl) + Tc[cb + kv];
  }
}

// ---------------- GLA pass C: per (b,h,chunk): o = tril(qe keT) v + qe h --
__global__ __launch_bounds__(256) void gla_passC_k(
    const float* __restrict__ qs, const float* __restrict__ ks,
    const float* __restrict__ v, const float* __restrict__ Gc,
    const float* __restrict__ hst, float* __restrict__ olin)
{
  int bx = blockIdx.x;            // (b*H+h)*NCH + c
  int c = bx & 31;
  int bh = bx >> 5;
  int b = bh >> 4, hq = bh & 15;
  int bkvh = b * HKVV + (hq >> 2);
  __shared__ float Qe[64][129];
  __shared__ float Ke[64][129];
  __shared__ float Vc[64][129];
  __shared__ float Am[64][65];
  size_t qrow = ((size_t)bh * SS + c * 64) * 128;
  size_t krow = ((size_t)bkvh * SS + c * 64) * 128;
  int tid = threadIdx.x;
  for (int e = tid; e < 64 * 128; e += 256) {
    int j = e >> 7, d = e & 127;
    float gc = Gc[krow + e];
    Qe[j][d] = qs[qrow + e] * expf(gc);
    Ke[j][d] = ks[krow + e] * expf(-gc);
    Vc[j][d] = v[krow + e];
  }
  __syncthreads();
  int i = tid >> 2, jg = tid & 3;
  {
    float acc[16];
    #pragma unroll
    for (int u = 0; u < 16; u++) acc[u] = 0.f;
    for (int d = 0; d < 128; d++) {
      float qv = Qe[i][d];
      #pragma unroll
      for (int u = 0; u < 16; u++) acc[u] += qv * Ke[jg * 16 + u][d];
    }
    #pragma unroll
    for (int u = 0; u < 16; u++) {
      int j = jg * 16 + u;
      Am[i][j] = (j <= i) ? acc[u] : 0.f;
    }
  }
  __syncthreads();
  {
    float acc[32];
    #pragma unroll
    for (int u = 0; u < 32; u++) acc[u] = 0.f;
    for (int j = 0; j < 64; j++) {
      float a = Am[i][j];
      #pragma unroll
      for (int u = 0; u < 32; u++) acc[u] += a * Vc[j][jg + 4 * u];
    }
    const float* hrow = hst + ((size_t)(bkvh * NCH + c) << 14);
    for (int k = 0; k < 128; k++) {
      float qv = Qe[i][k];
      #pragma unroll
      for (int u = 0; u < 32; u++) acc[u] += qv * hrow[k * 128 + jg + 4 * u];
    }
    size_t obase = qrow + (size_t)i * 128;
    #pragma unroll
    for (int u = 0; u < 32; u++) olin[obase + jg + 4 * u] = acc[u];
  }
}

// ---------------- windowed attention + mix + bf16 round (in place) -------
__global__ __launch_bounds__(256) void win_attn_k(
    const float* __restrict__ sq, const float* __restrict__ sk,
    const float* __restrict__ v, float* __restrict__ olin)
{
  int bx = blockIdx.x;            // (b*H+h)*NBLK + n
  int n = bx & 31;
  int bh = bx >> 5;
  int b = bh >> 4, hq = bh & 15;
  int bkvh = b * HKVV + (hq >> 2);
  __shared__ float Qs[64][129];
  __shared__ float KV[128][129];
  __shared__ float Sc[64][129];
  int tid = threadIdx.x;
  size_t qrow = ((size_t)bh * SS + n * 64) * 128;
  size_t krowbase = (size_t)bkvh * SS * 128;
  for (int e = tid; e < 64 * 128; e += 256) {
    int i2 = e >> 7, d = e & 127;
    Qs[i2][d] = sq[qrow + e];
  }
  for (int e = tid; e < 128 * 128; e += 256) {
    int j = e >> 7, d = e & 127;
    int kp = (n - 1) * 64 + j;
    KV[j][d] = (kp >= 0) ? sk[krowbase + (size_t)kp * 128 + d] : 0.f;
  }
  __syncthreads();
  int i = tid >> 2, jg = tid & 3;
  {
    float acc[32];
    #pragma unroll
    for (int u = 0; u < 32; u++) acc[u] = 0.f;
    for (int d = 0; d < 128; d++) {
      float qv = Qs[i][d];
      #pragma unroll
      for (int u = 0; u < 32; u++) acc[u] += qv * KV[jg + 4 * u][d];
    }
    const float scale = 0.08838834764831845f; // 1/sqrt(128)
    #pragma unroll
    for (int u = 0; u < 32; u++) {
      int j = jg + 4 * u;
      int kp = (n - 1) * 64 + j;
      bool valid = (j >= i) && (j <= i + 64) && (kp >= 0);
      Sc[i][j] = valid ? acc[u] * scale : -1e30f;
    }
  }
  __syncthreads();
  {
    int c0 = jg * 32;
    float m = -1e30f;
    #pragma unroll
    for (int cc = 0; cc < 32; cc++) m = fmaxf(m, Sc[i][c0 + cc]);
    m = fmaxf(m, __shfl_xor(m, 1));
    m = fmaxf(m, __shfl_xor(m, 2));
    float pv[32];
    float sum = 0.f;
    #pragma unroll
    for (int cc = 0; cc < 32; cc++) { pv[cc] = expf(Sc[i][c0 + cc] - m); sum += pv[cc]; }
    sum += __shfl_xor(sum, 1);
    sum += __shfl_xor(sum, 2);
    float inv = 1.0f / sum;
    #pragma unroll
    for (int cc = 0; cc < 32; cc++) Sc[i][c0 + cc] = pv[cc] * inv;
  }
  __syncthreads();
  for (int e = tid; e < 128 * 128; e += 256) {
    int j = e >> 7, d = e & 127;
    int kp = (n - 1) * 64 + j;
    KV[j][d] = (kp >= 0) ? v[krowbase + (size_t)kp * 128 + d] : 0.f;
  }
  __syncthreads();
  {
    float acc[32];
    #pragma unroll
    for (int u = 0; u < 32; u++) acc[u] = 0.f;
    for (int j = 0; j < 128; j++) {
      float p = Sc[i][j];
      #pragma unroll
      for (int u = 0; u < 32; u++) acc[u] += p * KV[j][jg + 4 * u];
    }
    size_t obase = qrow + (size_t)i * 128;
    #pragma unroll
    for (int u = 0; u < 32; u++) {
      int d = jg + 4 * u;
      float val = 0.5f * acc[u] + 0.5f * olin[obase + d];
      olin[obase + d] = __bfloat162float(__float2bfloat16(val));
    }
  }
}

// --------------------------------------------------------------------------
extern "C" void kernel_launch(void* const* d_in, const int* in_sizes, int n_in,
                              void* d_out, int out_size, void* d_ws, size_t ws_size,
                              hipStream_t stream)
{
  const float* hs = (const float*)d_in[0];
  const int*  pos = (const int*)d_in[1];
  const float* Wq = (const float*)d_in[2];
  const float* bq = (const float*)d_in[3];
  const float* Wk = (const float*)d_in[4];
  const float* bk = (const float*)d_in[5];
  const float* Wv = (const float*)d_in[6];
  const float* bv = (const float*)d_in[7];
  const float* Wo = (const float*)d_in[8];
  float* out = (float*)d_out;

  float* w = (float*)d_ws;
  const size_t QSZ = (size_t)BB * HH * SS * DD;         // 8388608
  const size_t KSZ = (size_t)BB * HKVV * SS * DD;       // 2097152
  const size_t TSZ = (size_t)BB * HKVV * NCH * DD * DD; // 4194304
  float* qbuf = w; w += QSZ;
  float* sq   = w; w += QSZ;
  float* olin = w; w += QSZ;
  float* kbuf = w; w += KSZ;
  float* sk   = w; w += KSZ;
  float* gbuf = w; w += KSZ;
  float* vbuf = w; w += KSZ;
  float* Gc   = w; w += KSZ;
  float* Tc   = w; w += TSZ;
  float* hst  = w; w += TSZ;
  float* ct   = w; w += (size_t)SS * 64;
  float* st   = w; w += (size_t)SS * 64;

  dim3 blk(256);
  const int M = BB * SS; // 4096

  // projections (head-layout store)
  gemm_bt_k<<<dim3(HIDN / 64, M / 64), blk, 0, stream>>>(hs, Wq, bq, qbuf, M, HH * DD, HIDN, 1, HH, 0);
  gemm_bt_k<<<dim3((HKVV * DD) / 64, M / 64), blk, 0, stream>>>(hs, Wk, bk, kbuf, M, HKVV * DD, HIDN, 1, HKVV, 0);
  gemm_bt_k<<<dim3((HKVV * DD) / 64, M / 64), blk, 0, stream>>>(hs, Wv, bv, vbuf, M, HKVV * DD, HIDN, 1, HKVV, 0);

  rope_tab_k<<<dim3((SS * 64) / 256), blk, 0, stream>>>(pos, ct, st);
  prep_q_k<<<dim3(BB * HH * SS / 4), blk, 0, stream>>>(qbuf, sq, ct, st);
  prep_k_k<<<dim3(BB * HKVV * SS / 4), blk, 0, stream>>>(kbuf, sk, gbuf, ct, st);

  gla_passA_k<<<dim3(BB * HKVV * NCH), blk, 0, stream>>>(kbuf, vbuf, gbuf, Gc, Tc);
  gla_passB_k<<<dim3(BB * HKVV * DD * DD / 256), blk, 0, stream>>>(Tc, Gc, hst);
  gla_passC_k<<<dim3(BB * HH * NCH), blk, 0, stream>>>(qbuf, kbuf, vbuf, Gc, hst, olin);

  win_attn_k<<<dim3(BB * HH * NBLK), blk, 0, stream>>>(sq, sk, vbuf, olin);

  // out = o_mix @ Wo^T  (head-strided A read, plain store)
  gemm_bt_k<<<dim3(HIDN / 64, M / 64), blk, 0, stream>>>(olin, Wo, nullptr, out, M, HIDN, HIDN, 0, 0, 1);
}

// Round 2
// 887.974 us; speedup vs baseline: 2.6085x; 2.6085x over previous
//
#include <hip/hip_runtime.h>
#include <hip/hip_bf16.h>
#include <math.h>

#define BB   2
#define SS   2048
#define HIDN 2048
#define HH   16
#define HKVV 4
#define DD   128
#define NCH  32   // S/CHUNK
#define CHK  64
#define NBLK 32   // S/WIN

typedef __attribute__((ext_vector_type(8))) short bf16x8;
typedef __attribute__((ext_vector_type(4))) float f32x4;

__device__ __forceinline__ short f2bf(float x)
{
  __hip_bfloat16 h = __float2bfloat16(x);
  return *(short*)&h;
}

__device__ __forceinline__ void gld_lds16(const short* g, short* lds)
{
  __builtin_amdgcn_global_load_lds(
      (const __attribute__((address_space(1))) void*)g,
      (__attribute__((address_space(3))) void*)lds, 16, 0, 0);
}

// ---------------- fp32 -> bf16 cast (vectorized) --------------------------
__global__ __launch_bounds__(256) void cast_bf16_k(const float* __restrict__ in,
    short* __restrict__ out, int n4)
{
  int i = blockIdx.x * 256 + threadIdx.x;
  if (i >= n4) return;
  const float4 v = ((const float4*)in)[i];
  short4 o;
  o.x = f2bf(v.x); o.y = f2bf(v.y); o.z = f2bf(v.z); o.w = f2bf(v.w);
  ((short4*)out)[i] = o;
}

// ---------------- bf16 MFMA GEMM: C = A * Bt^T (+bias) --------------------
// A: M x K bf16 row-major. Bt: N x K bf16 row-major.
// mode 0: plain f32 C[m*N+n]; mode 1: head store into (B,NH,S,D) f32.
// M%128==0, N%128==0, K%32==0.
__global__ __launch_bounds__(256) void mfma_gemm_bt(
    const short* __restrict__ A, const short* __restrict__ Bt,
    const float* __restrict__ bias, float* __restrict__ C,
    int M, int N, int K, int mode, int NH)
{
  __shared__ short As[128 * 32];
  __shared__ short Bs[128 * 32];
  int tid = threadIdx.x;
  int wave = tid >> 6, lane = tid & 63;
  int bm = blockIdx.y * 128, bn = blockIdx.x * 128;
  int wr = wave >> 1, wc = wave & 1;

  f32x4 acc[4][4];
  #pragma unroll
  for (int m = 0; m < 4; m++)
    #pragma unroll
    for (int n = 0; n < 4; n++) acc[m][n] = (f32x4){0.f, 0.f, 0.f, 0.f};

  int srow = lane >> 2;        // 0..15 within 16-row chunk
  int scol = (lane & 3) * 8;   // 0,8,16,24
  const short* Abase = A + (size_t)bm * K;
  const short* Bbase = Bt + (size_t)bn * K;

  for (int k0 = 0; k0 < K; k0 += 32) {
    #pragma unroll
    for (int t = wave; t < 8; t += 4) {
      gld_lds16(Abase + (size_t)(t * 16 + srow) * K + k0 + scol, &As[t * 512]);
      gld_lds16(Bbase + (size_t)(t * 16 + srow) * K + k0 + scol, &Bs[t * 512]);
    }
    __syncthreads();
    int koff = (lane >> 4) * 8;
    int ar = wr * 64 + (lane & 15);
    int br = wc * 64 + (lane & 15);
    bf16x8 af[4], bfr[4];
    #pragma unroll
    for (int m = 0; m < 4; m++) af[m] = *(const bf16x8*)&As[(ar + m * 16) * 32 + koff];
    #pragma unroll
    for (int n = 0; n < 4; n++) bfr[n] = *(const bf16x8*)&Bs[(br + n * 16) * 32 + koff];
    #pragma unroll
    for (int m = 0; m < 4; m++)
      #pragma unroll
      for (int n = 0; n < 4; n++)
        acc[m][n] = __builtin_amdgcn_mfma_f32_16x16x32_bf16(af[m], bfr[n], acc[m][n], 0, 0, 0);
    __syncthreads();
  }

  int crow0 = wr * 64 + (lane >> 4) * 4;
  int ccol0 = wc * 64 + (lane & 15);
  #pragma unroll
  for (int m = 0; m < 4; m++) {
    #pragma unroll
    for (int n = 0; n < 4; n++) {
      int nn = bn + ccol0 + n * 16;
      float bv = bias ? bias[nn] : 0.f;
      #pragma unroll
      for (int r = 0; r < 4; r++) {
        int mm = bm + crow0 + m * 16 + r;
        float val = acc[m][n][r] + bv;
        if (mode == 0) {
          C[(size_t)mm * N + nn] = val;
        } else {
          int b = mm >> 11, s = mm & 2047;
          int hh = nn >> 7, d = nn & 127;
          C[(size_t)((b * NH + hh) * SS + s) * DD + d] = val;
        }
      }
    }
  }
}

// ---------------- RoPE cos/sin table: (S x 64) ----------------------------
__global__ void rope_tab_k(const int* __restrict__ pos, float* __restrict__ ct,
                           float* __restrict__ st)
{
  int id = blockIdx.x * 256 + threadIdx.x;
  if (id >= SS * 64) return;
  int s = id >> 6, i = id & 63;
  double inv = pow(1.0e6, -(double)(2 * i) / 128.0);
  double ang = (double)pos[s] * inv;
  ct[id] = (float)cos(ang);
  st[id] = (float)sin(ang);
}

__device__ __forceinline__ float logsigf(float x)
{
  return (x >= 0.f) ? -log1pf(expf(-x)) : x - log1pf(expf(x));
}

// ---------------- prep q: softmax (in place) + rope -> sq -----------------
__global__ __launch_bounds__(256) void prep_q_k(float* __restrict__ q,
    float* __restrict__ sq, const float* __restrict__ ct, const float* __restrict__ st)
{
  int row = blockIdx.x * 4 + (threadIdx.x >> 6); // (b*H+h)*S + s
  int lane = threadIdx.x & 63;
  size_t base = (size_t)row * 128;
  int s = row & (SS - 1);
  float x0 = q[base + lane], x1 = q[base + 64 + lane];
  float m = fmaxf(x0, x1);
  for (int o = 32; o > 0; o >>= 1) m = fmaxf(m, __shfl_xor(m, o));
  float e0 = expf(x0 - m), e1 = expf(x1 - m);
  float sum = e0 + e1;
  for (int o = 32; o > 0; o >>= 1) sum += __shfl_xor(sum, o);
  float inv = 1.0f / sum;
  q[base + lane] = e0 * inv;
  q[base + 64 + lane] = e1 * inv;
  float c = ct[s * 64 + lane], sn = st[s * 64 + lane];
  sq[base + lane]      = x0 * c - x1 * sn;
  sq[base + 64 + lane] = x1 * c + x0 * sn;
}

// ---------------- prep k: softmax (in place) + gate + rope ----------------
__global__ __launch_bounds__(256) void prep_k_k(float* __restrict__ k,
    float* __restrict__ sk, float* __restrict__ g,
    const float* __restrict__ ct, const float* __restrict__ st)
{
  int row = blockIdx.x * 4 + (threadIdx.x >> 6); // (b*HKV+kv)*S + s
  int lane = threadIdx.x & 63;
  size_t base = (size_t)row * 128;
  int s = row & (SS - 1);
  float x0 = k[base + lane], x1 = k[base + 64 + lane];
  float m = fmaxf(x0, x1);
  for (int o = 32; o > 0; o >>= 1) m = fmaxf(m, __shfl_xor(m, o));
  float e0 = expf(x0 - m), e1 = expf(x1 - m);
  float sum = e0 + e1;
  for (int o = 32; o > 0; o >>= 1) sum += __shfl_xor(sum, o);
  float inv = 1.0f / sum;
  k[base + lane] = e0 * inv;
  k[base + 64 + lane] = e1 * inv;
  g[base + lane]      = logsigf(x0) * (1.0f / 16.0f);
  g[base + 64 + lane] = logsigf(x1) * (1.0f / 16.0f);
  float c = ct[s * 64 + lane], sn = st[s * 64 + lane];
  sk[base + lane]      = x0 * c - x1 * sn;
  sk[base + 64 + lane] = x1 * c + x0 * sn;
}

// ---------------- GLA pass A: per (b,kv,chunk): Gc cumsum + Tc ------------
__global__ __launch_bounds__(256) void gla_passA_k(
    const float* __restrict__ ks, const float* __restrict__ v,
    const float* __restrict__ g, float* __restrict__ Gc, float* __restrict__ Tc)
{
  int bx = blockIdx.x;             // bkvh*NCH + c
  int c = bx & 31;
  int bkvh = bx >> 5;
  __shared__ float Gs[64][128];
  __shared__ float Kg[64][128];
  __shared__ float Vs[64][128];
  size_t rowbase = ((size_t)bkvh * SS + c * 64) * 128;
  int tid = threadIdx.x;
  for (int e = tid; e < 64 * 128; e += 256) {
    int j = e >> 7, d = e & 127;
    Gs[j][d] = g[rowbase + e];
    Vs[j][d] = v[rowbase + e];
  }
  __syncthreads();
  if (tid < 128) {
    float run = 0.f;
    for (int j = 0; j < 64; j++) { run += Gs[j][tid]; Gs[j][tid] = run; }
  }
  __syncthreads();
  for (int e = tid; e < 64 * 128; e += 256) {
    int j = e >> 7, d = e & 127;
    float gc = Gs[j][d];
    Gc[rowbase + e] = gc;
    float gl = Gs[63][d];
    Kg[j][d] = ks[rowbase + e] * expf(gl - gc);
  }
  __syncthreads();
  int vcol = tid & 127, kgrp = tid >> 7;
  float acc[64];
  #pragma unroll
  for (int u = 0; u < 64; u++) acc[u] = 0.f;
  for (int j = 0; j < 64; j++) {
    float vv = Vs[j][vcol];
    #pragma unroll
    for (int u = 0; u < 64; u++) acc[u] += Kg[j][kgrp * 64 + u] * vv;
  }
  size_t tbase = (size_t)bx * 16384;
  for (int u = 0; u < 64; u++)
    Tc[tbase + (size_t)(kgrp * 64 + u) * 128 + vcol] = acc[u];
}

// ---------------- GLA pass B: parallel per-(k,v) scan over chunks ---------
__global__ __launch_bounds__(256) void gla_passB_k(
    const float* __restrict__ Tc, const float* __restrict__ Gc,
    float* __restrict__ hst)
{
  int id = blockIdx.x * 256 + threadIdx.x; // B*HKV*D*D
  int bkvh = id >> 14;
  int kv = id & 16383;
  int kk = kv >> 7;
  float h = 0.f;
  for (int c = 0; c < NCH; ++c) {
    size_t cb = ((size_t)(bkvh * NCH + c) << 14);
    hst[cb + kv] = h;
    float gl = Gc[((size_t)bkvh * SS + c * 64 + 63) * 128 + kk];
    h = h * expf(gl) + Tc[cb + kv];
  }
}

// ---------------- GLA pass C: per (b,h,chunk): o = tril(qe keT) v + qe h --
__global__ __launch_bounds__(256) void gla_passC_k(
    const float* __restrict__ qs, const float* __restrict__ ks,
    const float* __restrict__ v, const float* __restrict__ Gc,
    const float* __restrict__ hst, float* __restrict__ olin)
{
  int bx = blockIdx.x;            // (b*H+h)*NCH + c
  int c = bx & 31;
  int bh = bx >> 5;
  int b = bh >> 4, hq = bh & 15;
  int bkvh = b * HKVV + (hq >> 2);
  __shared__ float Qe[64][129];
  __shared__ float Ke[64][129];
  __shared__ float Vc[64][129];
  __shared__ float Am[64][65];
  size_t qrow = ((size_t)bh * SS + c * 64) * 128;
  size_t krow = ((size_t)bkvh * SS + c * 64) * 128;
  int tid = threadIdx.x;
  for (int e = tid; e < 64 * 128; e += 256) {
    int j = e >> 7, d = e & 127;
    float gc = Gc[krow + e];
    Qe[j][d] = qs[qrow + e] * expf(gc);
    Ke[j][d] = ks[krow + e] * expf(-gc);
    Vc[j][d] = v[krow + e];
  }
  __syncthreads();
  int i = tid >> 2, jg = tid & 3;
  {
    float acc[16];
    #pragma unroll
    for (int u = 0; u < 16; u++) acc[u] = 0.f;
    for (int d = 0; d < 128; d++) {
      float qv = Qe[i][d];
      #pragma unroll
      for (int u = 0; u < 16; u++) acc[u] += qv * Ke[jg * 16 + u][d];
    }
    #pragma unroll
    for (int u = 0; u < 16; u++) {
      int j = jg * 16 + u;
      Am[i][j] = (j <= i) ? acc[u] : 0.f;
    }
  }
  __syncthreads();
  {
    float acc[32];
    #pragma unroll
    for (int u = 0; u < 32; u++) acc[u] = 0.f;
    for (int j = 0; j < 64; j++) {
      float a = Am[i][j];
      #pragma unroll
      for (int u = 0; u < 32; u++) acc[u] += a * Vc[j][jg + 4 * u];
    }
    const float* hrow = hst + ((size_t)(bkvh * NCH + c) << 14);
    for (int k = 0; k < 128; k++) {
      float qv = Qe[i][k];
      #pragma unroll
      for (int u = 0; u < 32; u++) acc[u] += qv * hrow[k * 128 + jg + 4 * u];
    }
    size_t obase = qrow + (size_t)i * 128;
    #pragma unroll
    for (int u = 0; u < 32; u++) olin[obase + jg + 4 * u] = acc[u];
  }
}

// ---------------- windowed attention + mix -> bf16 (B,S,H*D) --------------
__global__ __launch_bounds__(256) void win_attn_k(
    const float* __restrict__ sq, const float* __restrict__ sk,
    const float* __restrict__ v, const float* __restrict__ olin,
    short* __restrict__ obf)
{
  int bx = blockIdx.x;            // (b*H+h)*NBLK + n
  int n = bx & 31;
  int bh = bx >> 5;
  int b = bh >> 4, hq = bh & 15;
  int bkvh = b * HKVV + (hq >> 2);
  __shared__ float Qs[64][129];
  __shared__ float KV[128][129];
  __shared__ float Sc[64][129];
  int tid = threadIdx.x;
  size_t qrow = ((size_t)bh * SS + n * 64) * 128;
  size_t krowbase = (size_t)bkvh * SS * 128;
  for (int e = tid; e < 64 * 128; e += 256) {
    int i2 = e >> 7, d = e & 127;
    Qs[i2][d] = sq[qrow + e];
  }
  for (int e = tid; e < 128 * 128; e += 256) {
    int j = e >> 7, d = e & 127;
    int kp = (n - 1) * 64 + j;
    KV[j][d] = (kp >= 0) ? sk[krowbase + (size_t)kp * 128 + d] : 0.f;
  }
  __syncthreads();
  int i = tid >> 2, jg = tid & 3;
  {
    float acc[32];
    #pragma unroll
    for (int u = 0; u < 32; u++) acc[u] = 0.f;
    for (int d = 0; d < 128; d++) {
      float qv = Qs[i][d];
      #pragma unroll
      for (int u = 0; u < 32; u++) acc[u] += qv * KV[jg + 4 * u][d];
    }
    const float scale = 0.08838834764831845f; // 1/sqrt(128)
    #pragma unroll
    for (int u = 0; u < 32; u++) {
      int j = jg + 4 * u;
      int kp = (n - 1) * 64 + j;
      bool valid = (j >= i) && (j <= i + 64) && (kp >= 0);
      Sc[i][j] = valid ? acc[u] * scale : -1e30f;
    }
  }
  __syncthreads();
  {
    int c0 = jg * 32;
    float m = -1e30f;
    #pragma unroll
    for (int cc = 0; cc < 32; cc++) m = fmaxf(m, Sc[i][c0 + cc]);
    m = fmaxf(m, __shfl_xor(m, 1));
    m = fmaxf(m, __shfl_xor(m, 2));
    float pv[32];
    float sum = 0.f;
    #pragma unroll
    for (int cc = 0; cc < 32; cc++) { pv[cc] = expf(Sc[i][c0 + cc] - m); sum += pv[cc]; }
    sum += __shfl_xor(sum, 1);
    sum += __shfl_xor(sum, 2);
    float inv = 1.0f / sum;
    #pragma unroll
    for (int cc = 0; cc < 32; cc++) Sc[i][c0 + cc] = pv[cc] * inv;
  }
  __syncthreads();
  for (int e = tid; e < 128 * 128; e += 256) {
    int j = e >> 7, d = e & 127;
    int kp = (n - 1) * 64 + j;
    KV[j][d] = (kp >= 0) ? v[krowbase + (size_t)kp * 128 + d] : 0.f;
  }
  __syncthreads();
  {
    float acc[32];
    #pragma unroll
    for (int u = 0; u < 32; u++) acc[u] = 0.f;
    for (int j = 0; j < 128; j++) {
      float p = Sc[i][j];
      #pragma unroll
      for (int u = 0; u < 32; u++) acc[u] += p * KV[j][jg + 4 * u];
    }
    size_t obase = qrow + (size_t)i * 128;
    size_t ob = ((size_t)(b * SS + (n * 64 + i))) * HIDN + hq * 128;
    #pragma unroll
    for (int u = 0; u < 32; u++) {
      int d = jg + 4 * u;
      float val = 0.5f * acc[u] + 0.5f * olin[obase + d];
      obf[ob + d] = f2bf(val);
    }
  }
}

// --------------------------------------------------------------------------
extern "C" void kernel_launch(void* const* d_in, const int* in_sizes, int n_in,
                              void* d_out, int out_size, void* d_ws, size_t ws_size,
                              hipStream_t stream)
{
  const float* hs = (const float*)d_in[0];
  const int*  pos = (const int*)d_in[1];
  const float* Wq = (const float*)d_in[2];
  const float* bq = (const float*)d_in[3];
  const float* Wk = (const float*)d_in[4];
  const float* bk = (const float*)d_in[5];
  const float* Wv = (const float*)d_in[6];
  const float* bv = (const float*)d_in[7];
  const float* Wo = (const float*)d_in[8];
  float* out = (float*)d_out;

  float* w = (float*)d_ws;
  const size_t QSZ = (size_t)BB * HH * SS * DD;         // 8388608
  const size_t KSZ = (size_t)BB * HKVV * SS * DD;       // 2097152
  const size_t TSZ = (size_t)BB * HKVV * NCH * DD * DD; // 4194304
  float* qbuf = w; w += QSZ;
  float* sq   = w; w += QSZ;   // also hosts wq_bf/wk_bf/wv_bf (dead before prep_q writes sq)
  float* olin = w; w += QSZ;   // also hosts hs_bf (dead before gla_passC writes olin)
  float* kbuf = w; w += KSZ;
  float* sk   = w; w += KSZ;
  float* gbuf = w; w += KSZ;
  float* vbuf = w; w += KSZ;
  float* Gc   = w; w += KSZ;
  float* Tc   = w; w += TSZ;   // also hosts obf (Tc dead after gla_passB)
  float* hst  = w; w += TSZ;
  float* ct   = w; w += (size_t)SS * 64;
  float* st   = w; w += (size_t)SS * 64;
  short* wo_bf = (short*)w; w += (size_t)HIDN * HIDN / 2; // 4194304 shorts

  short* hs_bf = (short*)olin;                 // 8388608 shorts, 16.8MB < 33.6MB
  short* wq_bf = (short*)sq;                   // 4194304 shorts
  short* wk_bf = wq_bf + (size_t)4194304;      // 1048576 shorts
  short* wv_bf = wk_bf + (size_t)1048576;      // 1048576 shorts (12.6MB < 33.6MB)
  short* obf   = (short*)Tc;                   // 8388608 shorts = 16.8MB == TSZ*4B

  dim3 blk(256);
  const int M = BB * SS; // 4096

  // fp32 -> bf16 casts
  cast_bf16_k<<<dim3(8192), blk, 0, stream>>>(hs, hs_bf, (int)(QSZ / 4));
  cast_bf16_k<<<dim3(4096), blk, 0, stream>>>(Wq, wq_bf, 4194304 / 4);
  cast_bf16_k<<<dim3(1024), blk, 0, stream>>>(Wk, wk_bf, 1048576 / 4);
  cast_bf16_k<<<dim3(1024), blk, 0, stream>>>(Wv, wv_bf, 1048576 / 4);
  cast_bf16_k<<<dim3(4096), blk, 0, stream>>>(Wo, wo_bf, 4194304 / 4);

  // projections (head-layout store, f32 out)
  mfma_gemm_bt<<<dim3(HIDN / 128, M / 128), blk, 0, stream>>>(hs_bf, wq_bf, bq, qbuf, M, HH * DD, HIDN, 1, HH);
  mfma_gemm_bt<<<dim3((HKVV * DD) / 128, M / 128), blk, 0, stream>>>(hs_bf, wk_bf, bk, kbuf, M, HKVV * DD, HIDN, 1, HKVV);
  mfma_gemm_bt<<<dim3((HKVV * DD) / 128, M / 128), blk, 0, stream>>>(hs_bf, wv_bf, bv, vbuf, M, HKVV * DD, HIDN, 1, HKVV);

  rope_tab_k<<<dim3((SS * 64) / 256), blk, 0, stream>>>(pos, ct, st);
  prep_q_k<<<dim3(BB * HH * SS / 4), blk, 0, stream>>>(qbuf, sq, ct, st);
  prep_k_k<<<dim3(BB * HKVV * SS / 4), blk, 0, stream>>>(kbuf, sk, gbuf, ct, st);

  gla_passA_k<<<dim3(BB * HKVV * NCH), blk, 0, stream>>>(kbuf, vbuf, gbuf, Gc, Tc);
  gla_passB_k<<<dim3(BB * HKVV * DD * DD / 256), blk, 0, stream>>>(Tc, Gc, hst);
  gla_passC_k<<<dim3(BB * HH * NCH), blk, 0, stream>>>(qbuf, kbuf, vbuf, Gc, hst, olin);

  win_attn_k<<<dim3(BB * HH * NBLK), blk, 0, stream>>>(sq, sk, vbuf, olin, obf);

  // out = o_mix @ Wo^T  (row-major bf16 A, plain f32 store)
  mfma_gemm_bt<<<dim3(HIDN / 128, M / 128), blk, 0, stream>>>(obf, wo_bf, nullptr, out, M, HIDN, HIDN, 0, 0);
}

// Round 3
// 358.583 us; speedup vs baseline: 6.4595x; 2.4763x over previous
//
#include <hip/hip_runtime.h>
#include <hip/hip_bf16.h>
#include <math.h>

#define BB   2
#define SS   2048
#define HIDN 2048
#define HH   16
#define HKVV 4
#define DD   128
#define NCH  32   // S/CHUNK
#define CHK  64
#define NBLK 32   // S/WIN

typedef __attribute__((ext_vector_type(8))) short bf16x8;
typedef __attribute__((ext_vector_type(4))) float f32x4;

__device__ __forceinline__ short f2bf(float x)
{
  __hip_bfloat16 h = __float2bfloat16(x);
  return *(short*)&h;
}

__device__ __forceinline__ uint packbf(float a, float b)
{
  return (uint)(ushort)f2bf(a) | ((uint)(ushort)f2bf(b) << 16);
}

__device__ __forceinline__ void gld_lds16(const short* g, short* lds)
{
  __builtin_amdgcn_global_load_lds(
      (const __attribute__((address_space(1))) void*)g,
      (__attribute__((address_space(3))) void*)lds, 16, 0, 0);
}

// swizzled LDS helpers: byte ^= ((row&7)<<4) within each 8-row stripe
__device__ __forceinline__ bf16x8 ldsA(const short* base, int row, int rs, int ks)
{
  int byte = (row * rs + ks) * 2;
  byte ^= ((row & 7) << 4);
  __builtin_assume((byte & 15) == 0);
  return *(const bf16x8*)((const char*)base + byte);
}
__device__ __forceinline__ void lds_w32_swz(short* base, int row, int rs, int ks, uint v)
{
  int byte = (row * rs + ks) * 2;
  byte ^= ((row & 7) << 4);
  *(uint*)((char*)base + byte) = v;
}
__device__ __forceinline__ void lds_w16_swz(short* base, int row, int rs, int ks, short v)
{
  int byte = (row * rs + ks) * 2;
  byte ^= ((row & 7) << 4);
  *(short*)((char*)base + byte) = v;
}

// ---------------- fp32 -> bf16 cast (vectorized) --------------------------
__global__ __launch_bounds__(256) void cast_bf16_k(const float* __restrict__ in,
    short* __restrict__ out, int n4)
{
  int i = blockIdx.x * 256 + threadIdx.x;
  if (i >= n4) return;
  const float4 v = ((const float4*)in)[i];
  short4 o;
  o.x = f2bf(v.x); o.y = f2bf(v.y); o.z = f2bf(v.z); o.w = f2bf(v.w);
  ((short4*)out)[i] = o;
}

// ---------------- bf16 MFMA GEMM: C = A * Bt^T (+bias) --------------------
__global__ __launch_bounds__(256) void mfma_gemm_bt(
    const short* __restrict__ A, const short* __restrict__ Bt,
    const float* __restrict__ bias, float* __restrict__ C,
    int M, int N, int K, int mode, int NH)
{
  __shared__ short As[128 * 32];
  __shared__ short Bs[128 * 32];
  int tid = threadIdx.x;
  int wave = tid >> 6, lane = tid & 63;
  int bm = blockIdx.y * 128, bn = blockIdx.x * 128;
  int wr = wave >> 1, wc = wave & 1;

  f32x4 acc[4][4];
  #pragma unroll
  for (int m = 0; m < 4; m++)
    #pragma unroll
    for (int n = 0; n < 4; n++) acc[m][n] = (f32x4){0.f, 0.f, 0.f, 0.f};

  int srow = lane >> 2;
  int scol = (lane & 3) * 8;
  const short* Abase = A + (size_t)bm * K;
  const short* Bbase = Bt + (size_t)bn * K;

  for (int k0 = 0; k0 < K; k0 += 32) {
    #pragma unroll
    for (int t = wave; t < 8; t += 4) {
      gld_lds16(Abase + (size_t)(t * 16 + srow) * K + k0 + scol, &As[t * 512]);
      gld_lds16(Bbase + (size_t)(t * 16 + srow) * K + k0 + scol, &Bs[t * 512]);
    }
    __syncthreads();
    int koff = (lane >> 4) * 8;
    int ar = wr * 64 + (lane & 15);
    int br = wc * 64 + (lane & 15);
    bf16x8 af[4], bfr[4];
    #pragma unroll
    for (int m = 0; m < 4; m++) af[m] = *(const bf16x8*)&As[(ar + m * 16) * 32 + koff];
    #pragma unroll
    for (int n = 0; n < 4; n++) bfr[n] = *(const bf16x8*)&Bs[(br + n * 16) * 32 + koff];
    #pragma unroll
    for (int m = 0; m < 4; m++)
      #pragma unroll
      for (int n = 0; n < 4; n++)
        acc[m][n] = __builtin_amdgcn_mfma_f32_16x16x32_bf16(af[m], bfr[n], acc[m][n], 0, 0, 0);
    __syncthreads();
  }

  int crow0 = wr * 64 + (lane >> 4) * 4;
  int ccol0 = wc * 64 + (lane & 15);
  #pragma unroll
  for (int m = 0; m < 4; m++) {
    #pragma unroll
    for (int n = 0; n < 4; n++) {
      int nn = bn + ccol0 + n * 16;
      float bv = bias ? bias[nn] : 0.f;
      #pragma unroll
      for (int r = 0; r < 4; r++) {
        int mm = bm + crow0 + m * 16 + r;
        float val = acc[m][n][r] + bv;
        if (mode == 0) {
          C[(size_t)mm * N + nn] = val;
        } else {
          int b = mm >> 11, s = mm & 2047;
          int hh = nn >> 7, d = nn & 127;
          C[(size_t)((b * NH + hh) * SS + s) * DD + d] = val;
        }
      }
    }
  }
}

// ---------------- RoPE cos/sin table: (S x 64) ----------------------------
__global__ void rope_tab_k(const int* __restrict__ pos, float* __restrict__ ct,
                           float* __restrict__ st)
{
  int id = blockIdx.x * 256 + threadIdx.x;
  if (id >= SS * 64) return;
  int s = id >> 6, i = id & 63;
  double inv = pow(1.0e6, -(double)(2 * i) / 128.0);
  double ang = (double)pos[s] * inv;
  ct[id] = (float)cos(ang);
  st[id] = (float)sin(ang);
}

__device__ __forceinline__ float logsigf(float x)
{
  return (x >= 0.f) ? -log1pf(expf(-x)) : x - log1pf(expf(x));
}

// ---------------- prep q: softmax (in place) + rope -> sqb (bf16) ---------
__global__ __launch_bounds__(256) void prep_q_k(float* __restrict__ q,
    short* __restrict__ sqb, const float* __restrict__ ct, const float* __restrict__ st)
{
  int row = blockIdx.x * 4 + (threadIdx.x >> 6);
  int lane = threadIdx.x & 63;
  size_t base = (size_t)row * 128;
  int s = row & (SS - 1);
  float x0 = q[base + lane], x1 = q[base + 64 + lane];
  float m = fmaxf(x0, x1);
  for (int o = 32; o > 0; o >>= 1) m = fmaxf(m, __shfl_xor(m, o));
  float e0 = expf(x0 - m), e1 = expf(x1 - m);
  float sum = e0 + e1;
  for (int o = 32; o > 0; o >>= 1) sum += __shfl_xor(sum, o);
  float inv = 1.0f / sum;
  q[base + lane] = e0 * inv;
  q[base + 64 + lane] = e1 * inv;
  float c = ct[s * 64 + lane], sn = st[s * 64 + lane];
  sqb[base + lane]      = f2bf(x0 * c - x1 * sn);
  sqb[base + 64 + lane] = f2bf(x1 * c + x0 * sn);
}

// ---------------- prep k: softmax + gate + rope -> skb (bf16) -------------
__global__ __launch_bounds__(256) void prep_k_k(float* __restrict__ k,
    short* __restrict__ skb, float* __restrict__ g,
    const float* __restrict__ ct, const float* __restrict__ st)
{
  int row = blockIdx.x * 4 + (threadIdx.x >> 6);
  int lane = threadIdx.x & 63;
  size_t base = (size_t)row * 128;
  int s = row & (SS - 1);
  float x0 = k[base + lane], x1 = k[base + 64 + lane];
  float m = fmaxf(x0, x1);
  for (int o = 32; o > 0; o >>= 1) m = fmaxf(m, __shfl_xor(m, o));
  float e0 = expf(x0 - m), e1 = expf(x1 - m);
  float sum = e0 + e1;
  for (int o = 32; o > 0; o >>= 1) sum += __shfl_xor(sum, o);
  float inv = 1.0f / sum;
  k[base + lane] = e0 * inv;
  k[base + 64 + lane] = e1 * inv;
  g[base + lane]      = logsigf(x0) * (1.0f / 16.0f);
  g[base + 64 + lane] = logsigf(x1) * (1.0f / 16.0f);
  float c = ct[s * 64 + lane], sn = st[s * 64 + lane];
  skb[base + lane]      = f2bf(x0 * c - x1 * sn);
  skb[base + 64 + lane] = f2bf(x1 * c + x0 * sn);
}

// ---------------- GLA pass A: per (b,kv,chunk): Gc cumsum + Tc ------------
__global__ __launch_bounds__(256) void gla_passA_k(
    const float* __restrict__ ks, const float* __restrict__ v,
    const float* __restrict__ g, float* __restrict__ Gc, float* __restrict__ Tc)
{
  int bx = blockIdx.x;
  int c = bx & 31;
  int bkvh = bx >> 5;
  __shared__ float Gs[64][128];
  __shared__ float Kg[64][128];
  __shared__ float Vs[64][128];
  size_t rowbase = ((size_t)bkvh * SS + c * 64) * 128;
  int tid = threadIdx.x;
  for (int e = tid; e < 64 * 128; e += 256) {
    int j = e >> 7, d = e & 127;
    Gs[j][d] = g[rowbase + e];
    Vs[j][d] = v[rowbase + e];
  }
  __syncthreads();
  if (tid < 128) {
    float run = 0.f;
    for (int j = 0; j < 64; j++) { run += Gs[j][tid]; Gs[j][tid] = run; }
  }
  __syncthreads();
  for (int e = tid; e < 64 * 128; e += 256) {
    int j = e >> 7, d = e & 127;
    float gc = Gs[j][d];
    Gc[rowbase + e] = gc;
    float gl = Gs[63][d];
    Kg[j][d] = ks[rowbase + e] * expf(gl - gc);
  }
  __syncthreads();
  int vcol = tid & 127, kgrp = tid >> 7;
  float acc[64];
  #pragma unroll
  for (int u = 0; u < 64; u++) acc[u] = 0.f;
  for (int j = 0; j < 64; j++) {
    float vv = Vs[j][vcol];
    #pragma unroll
    for (int u = 0; u < 64; u++) acc[u] += Kg[j][kgrp * 64 + u] * vv;
  }
  size_t tbase = (size_t)bx * 16384;
  for (int u = 0; u < 64; u++)
    Tc[tbase + (size_t)(kgrp * 64 + u) * 128 + vcol] = acc[u];
}

// ---------------- GLA pass B: scan; writes hT[v][k] bf16 -------------------
__global__ __launch_bounds__(256) void gla_passB_k(
    const float* __restrict__ Tc, const float* __restrict__ Gc,
    short* __restrict__ hT)
{
  int id = blockIdx.x * 256 + threadIdx.x; // (bkvh, v, k)
  int bkvh = id >> 14;
  int vk = id & 16383;
  int vv = vk >> 7, kk = vk & 127;
  float h = 0.f;
  for (int c = 0; c < NCH; ++c) {
    size_t cb = ((size_t)(bkvh * NCH + c) << 14);
    hT[cb + vk] = f2bf(h);
    float gl = Gc[((size_t)bkvh * SS + c * 64 + 63) * 128 + kk];
    h = h * expf(gl) + Tc[cb + (size_t)kk * 128 + vv];
  }
}

// ---------------- GLA pass C (MFMA): o = tril(qe keT) v + qe h ------------
__global__ __launch_bounds__(256) void gla_passC_k(
    const float* __restrict__ qs, const float* __restrict__ ks,
    const float* __restrict__ v, const float* __restrict__ Gc,
    const short* __restrict__ hT, float* __restrict__ olin)
{
  int bx = blockIdx.x;            // (b*H+h)*NCH + c
  int c = bx & 31;
  int bh = bx >> 5;
  int b = bh >> 4, hq = bh & 15;
  int bkvh = b * HKVV + (hq >> 2);
  __shared__ short QeB[64 * 128];
  __shared__ short KeB[64 * 128];  // first 4096 reused as AmB after B1
  __shared__ short VtB[128 * 64];
  int tid = threadIdx.x, w = tid >> 6, l = tid & 63, g = l >> 4;
  size_t qrow = ((size_t)bh * SS + c * 64) * 128;
  size_t krow = ((size_t)bkvh * SS + c * 64) * 128;

  // preload h^T B-fragments from global (bf16, [v][k] rows k-contiguous)
  const short* hTb = hT + (((size_t)(bkvh * NCH + c)) << 14);
  bf16x8 hB[4][2];
  #pragma unroll
  for (int k0i = 0; k0i < 4; k0i++)
    #pragma unroll
    for (int nt = 0; nt < 2; nt++)
      hB[k0i][nt] = *(const bf16x8*)(hTb + (size_t)(32 * w + 16 * nt + (l & 15)) * 128 + k0i * 32 + g * 8);

  // staging: thread -> row j = tid>>2, d-block (tid&3)*32
  {
    int j = tid >> 2, d0 = (tid & 3) * 32;
    const float4* q4 = (const float4*)(qs + qrow + j * 128 + d0);
    const float4* k4 = (const float4*)(ks + krow + j * 128 + d0);
    const float4* g4 = (const float4*)(Gc + krow + j * 128 + d0);
    const float4* v4 = (const float4*)(v + krow + j * 128 + d0);
    #pragma unroll
    for (int u = 0; u < 8; u++) {
      float4 qv = q4[u], kv = k4[u], gv = g4[u], vv = v4[u];
      float e0 = __expf(gv.x), e1 = __expf(gv.y), e2 = __expf(gv.z), e3 = __expf(gv.w);
      lds_w32_swz(QeB, j, 128, d0 + 4 * u,     packbf(qv.x * e0, qv.y * e1));
      lds_w32_swz(QeB, j, 128, d0 + 4 * u + 2, packbf(qv.z * e2, qv.w * e3));
      lds_w32_swz(KeB, j, 128, d0 + 4 * u,     packbf(kv.x / e0, kv.y / e1));
      lds_w32_swz(KeB, j, 128, d0 + 4 * u + 2, packbf(kv.z / e2, kv.w / e3));
      lds_w16_swz(VtB, d0 + 4 * u + 0, 64, j, f2bf(vv.x));
      lds_w16_swz(VtB, d0 + 4 * u + 1, 64, j, f2bf(vv.y));
      lds_w16_swz(VtB, d0 + 4 * u + 2, 64, j, f2bf(vv.z));
      lds_w16_swz(VtB, d0 + 4 * u + 3, 64, j, f2bf(vv.w));
    }
  }
  __syncthreads(); // B0

  // A1 = qe * ke^T : wave w owns cols [16w, 16w+16)
  f32x4 acc1[4];
  #pragma unroll
  for (int m = 0; m < 4; m++) acc1[m] = (f32x4){0.f, 0.f, 0.f, 0.f};
  #pragma unroll
  for (int k0i = 0; k0i < 4; k0i++) {
    int k0 = k0i * 32 + g * 8;
    bf16x8 bk = ldsA(KeB, 16 * w + (l & 15), 128, k0);
    #pragma unroll
    for (int m = 0; m < 4; m++) {
      bf16x8 af = ldsA(QeB, 16 * m + (l & 15), 128, k0);
      acc1[m] = __builtin_amdgcn_mfma_f32_16x16x32_bf16(af, bk, acc1[m], 0, 0, 0);
    }
  }
  __syncthreads(); // B1: all KeB reads done
  short* AmB = KeB;
  #pragma unroll
  for (int m = 0; m < 4; m++)
    #pragma unroll
    for (int r = 0; r < 4; r++) {
      int i = 16 * m + 4 * g + r;
      int j = 16 * w + (l & 15);
      float val = (j <= i) ? acc1[m][r] : 0.f;
      lds_w16_swz(AmB, i, 64, j, f2bf(val));
    }
  __syncthreads(); // B2

  f32x4 acc[4][2];
  #pragma unroll
  for (int m = 0; m < 4; m++)
    #pragma unroll
    for (int nt = 0; nt < 2; nt++) acc[m][nt] = (f32x4){0.f, 0.f, 0.f, 0.f};
  // O1 = Am * V  (K=64)
  #pragma unroll
  for (int k0i = 0; k0i < 2; k0i++) {
    int k0 = k0i * 32 + g * 8;
    bf16x8 bfr[2];
    #pragma unroll
    for (int nt = 0; nt < 2; nt++) bfr[nt] = ldsA(VtB, 32 * w + 16 * nt + (l & 15), 64, k0);
    #pragma unroll
    for (int m = 0; m < 4; m++) {
      bf16x8 af = ldsA(AmB, 16 * m + (l & 15), 64, k0);
      #pragma unroll
      for (int nt = 0; nt < 2; nt++)
        acc[m][nt] = __builtin_amdgcn_mfma_f32_16x16x32_bf16(af, bfr[nt], acc[m][nt], 0, 0, 0);
    }
  }
  // O2 = qe * h  (K=128)
  #pragma unroll
  for (int k0i = 0; k0i < 4; k0i++) {
    int k0 = k0i * 32 + g * 8;
    #pragma unroll
    for (int m = 0; m < 4; m++) {
      bf16x8 af = ldsA(QeB, 16 * m + (l & 15), 128, k0);
      #pragma unroll
      for (int nt = 0; nt < 2; nt++)
        acc[m][nt] = __builtin_amdgcn_mfma_f32_16x16x32_bf16(af, hB[k0i][nt], acc[m][nt], 0, 0, 0);
    }
  }
  #pragma unroll
  for (int m = 0; m < 4; m++)
    #pragma unroll
    for (int nt = 0; nt < 2; nt++)
      #pragma unroll
      for (int r = 0; r < 4; r++) {
        int i = 16 * m + 4 * g + r, d = 32 * w + 16 * nt + (l & 15);
        olin[qrow + (size_t)i * 128 + d] = acc[m][nt][r];
      }
}

// ---------------- windowed attention (MFMA) + mix -> bf16 (B,S,H*D) -------
__global__ __launch_bounds__(256) void win_attn_k(
    const short* __restrict__ sqb, const short* __restrict__ skb,
    const short* __restrict__ vb, const float* __restrict__ olin,
    short* __restrict__ obf)
{
  int bx = blockIdx.x;            // (b*H+h)*NBLK + n
  int n = bx & 31;
  int bh = bx >> 5;
  int b = bh >> 4, hq = bh & 15;
  int bkvh = b * HKVV + (hq >> 2);
  __shared__ short Qs[64 * 128];   // then P (bf16)
  __shared__ short Ks[128 * 128];  // then V^T (bf16)
  __shared__ float wred[2][4][64];
  int tid = threadIdx.x, w = tid >> 6, l = tid & 63, g = l >> 4;
  const short* qg = sqb + ((size_t)bh * SS + n * 64) * 128;
  const short* kg = skb + (size_t)bkvh * SS * 128 + (ptrdiff_t)(n - 1) * 64 * 128;

  // stage Q (64x128) and K window (128x128), swizzled via pre-swizzled source
  for (int c0 = w * 64; c0 < 1024; c0 += 256) {
    int cc = c0 + l, row = cc >> 4;
    int gb = (cc << 4) ^ ((row & 7) << 4);
    gld_lds16((const short*)((const char*)qg + gb), Qs + c0 * 8);
  }
  for (int c0 = w * 64; c0 < 2048; c0 += 256) {
    int cc = c0 + l, row = cc >> 4;
    int gb = (cc << 4) ^ ((row & 7) << 4);
    gld_lds16((const short*)((const char*)kg + gb), Ks + c0 * 8);
  }
  __syncthreads(); // B0

  // QK^T: wave w owns key-cols [32w, 32w+32)
  f32x4 acc[4][2];
  #pragma unroll
  for (int m = 0; m < 4; m++)
    #pragma unroll
    for (int nt = 0; nt < 2; nt++) acc[m][nt] = (f32x4){0.f, 0.f, 0.f, 0.f};
  #pragma unroll
  for (int k0i = 0; k0i < 4; k0i++) {
    int k0 = k0i * 32 + g * 8;
    bf16x8 bfr[2];
    #pragma unroll
    for (int nt = 0; nt < 2; nt++) bfr[nt] = ldsA(Ks, 32 * w + 16 * nt + (l & 15), 128, k0);
    #pragma unroll
    for (int m = 0; m < 4; m++) {
      bf16x8 af = ldsA(Qs, 16 * m + (l & 15), 128, k0);
      #pragma unroll
      for (int nt = 0; nt < 2; nt++)
        acc[m][nt] = __builtin_amdgcn_mfma_f32_16x16x32_bf16(af, bfr[nt], acc[m][nt], 0, 0, 0);
    }
  }

  // mask + scale in-register; per-row partial max
  const float scale = 0.08838834764831845f;
  float mx[4][4];
  #pragma unroll
  for (int m = 0; m < 4; m++)
    #pragma unroll
    for (int r = 0; r < 4; r++) mx[m][r] = -1e30f;
  #pragma unroll
  for (int m = 0; m < 4; m++)
    #pragma unroll
    for (int nt = 0; nt < 2; nt++)
      #pragma unroll
      for (int r = 0; r < 4; r++) {
        int i = 16 * m + 4 * g + r;
        int j = 32 * w + 16 * nt + (l & 15);
        int kp = (n - 1) * 64 + j;
        bool valid = (j >= i) && (j <= i + 64) && (kp >= 0);
        float sc = valid ? acc[m][nt][r] * scale : -1e30f;
        acc[m][nt][r] = sc;
        mx[m][r] = fmaxf(mx[m][r], sc);
      }
  #pragma unroll
  for (int m = 0; m < 4; m++)
    #pragma unroll
    for (int r = 0; r < 4; r++) {
      #pragma unroll
      for (int msk = 1; msk < 16; msk <<= 1) mx[m][r] = fmaxf(mx[m][r], __shfl_xor(mx[m][r], msk));
    }
  if ((l & 15) == 0)
    #pragma unroll
    for (int m = 0; m < 4; m++)
      #pragma unroll
      for (int r = 0; r < 4; r++) wred[0][w][16 * m + 4 * g + r] = mx[m][r];
  __syncthreads(); // B1

  float mrow[4][4], sm[4][4];
  #pragma unroll
  for (int m = 0; m < 4; m++)
    #pragma unroll
    for (int r = 0; r < 4; r++) {
      int i = 16 * m + 4 * g + r;
      mrow[m][r] = fmaxf(fmaxf(wred[0][0][i], wred[0][1][i]), fmaxf(wred[0][2][i], wred[0][3][i]));
      sm[m][r] = 0.f;
    }
  #pragma unroll
  for (int m = 0; m < 4; m++)
    #pragma unroll
    for (int nt = 0; nt < 2; nt++)
      #pragma unroll
      for (int r = 0; r < 4; r++) {
        float p = __expf(acc[m][nt][r] - mrow[m][r]);
        acc[m][nt][r] = p;
        sm[m][r] += p;
      }
  #pragma unroll
  for (int m = 0; m < 4; m++)
    #pragma unroll
    for (int r = 0; r < 4; r++) {
      #pragma unroll
      for (int msk = 1; msk < 16; msk <<= 1) sm[m][r] += __shfl_xor(sm[m][r], msk);
    }
  if ((l & 15) == 0)
    #pragma unroll
    for (int m = 0; m < 4; m++)
      #pragma unroll
      for (int r = 0; r < 4; r++) wred[1][w][16 * m + 4 * g + r] = sm[m][r];
  __syncthreads(); // B2

  // write P (bf16) over Qs; stage V^T (bf16) over Ks
  #pragma unroll
  for (int m = 0; m < 4; m++)
    #pragma unroll
    for (int r = 0; r < 4; r++) {
      int i = 16 * m + 4 * g + r;
      float s = wred[1][0][i] + wred[1][1][i] + wred[1][2][i] + wred[1][3][i];
      float inv = 1.0f / s;
      #pragma unroll
      for (int nt = 0; nt < 2; nt++) {
        int j = 32 * w + 16 * nt + (l & 15);
        lds_w16_swz(Qs, i, 128, j, f2bf(acc[m][nt][r] * inv));
      }
    }
  {
    int j = tid >> 1, dh = (tid & 1) * 64;
    int kp = (n - 1) * 64 + j;
    const short* vrow = vb + ((size_t)bkvh * SS + kp) * 128 + dh;
    #pragma unroll
    for (int u = 0; u < 8; u++) {
      bf16x8 vv;
      if (kp >= 0) vv = *(const bf16x8*)(vrow + u * 8);
      else vv = (bf16x8){0, 0, 0, 0, 0, 0, 0, 0};
      #pragma unroll
      for (int i2 = 0; i2 < 8; i2++)
        lds_w16_swz(Ks, dh + u * 8 + i2, 128, j, vv[i2]);
    }
  }
  __syncthreads(); // B3

  // PV: O = P (64x128) * V (128x128), B = V^T rows d
  f32x4 o[4][2];
  #pragma unroll
  for (int m = 0; m < 4; m++)
    #pragma unroll
    for (int nt = 0; nt < 2; nt++) o[m][nt] = (f32x4){0.f, 0.f, 0.f, 0.f};
  #pragma unroll
  for (int k0i = 0; k0i < 4; k0i++) {
    int k0 = k0i * 32 + g * 8;
    bf16x8 bfr[2];
    #pragma unroll
    for (int nt = 0; nt < 2; nt++) bfr[nt] = ldsA(Ks, 32 * w + 16 * nt + (l & 15), 128, k0);
    #pragma unroll
    for (int m = 0; m < 4; m++) {
      bf16x8 af = ldsA(Qs, 16 * m + (l & 15), 128, k0);
      #pragma unroll
      for (int nt = 0; nt < 2; nt++)
        o[m][nt] = __builtin_amdgcn_mfma_f32_16x16x32_bf16(af, bfr[nt], o[m][nt], 0, 0, 0);
    }
  }
  // epilogue: mix with olin, write bf16 (B,S,H*D)
  #pragma unroll
  for (int m = 0; m < 4; m++)
    #pragma unroll
    for (int nt = 0; nt < 2; nt++)
      #pragma unroll
      for (int r = 0; r < 4; r++) {
        int i = 16 * m + 4 * g + r, d = 32 * w + 16 * nt + (l & 15);
        float val = 0.5f * o[m][nt][r] + 0.5f * olin[((size_t)bh * SS + n * 64 + i) * 128 + d];
        obf[((size_t)(b * SS + n * 64 + i)) * HIDN + hq * 128 + d] = f2bf(val);
      }
}

// --------------------------------------------------------------------------
extern "C" void kernel_launch(void* const* d_in, const int* in_sizes, int n_in,
                              void* d_out, int out_size, void* d_ws, size_t ws_size,
                              hipStream_t stream)
{
  const float* hs = (const float*)d_in[0];
  const int*  pos = (const int*)d_in[1];
  const float* Wq = (const float*)d_in[2];
  const float* bq = (const float*)d_in[3];
  const float* Wk = (const float*)d_in[4];
  const float* bk = (const float*)d_in[5];
  const float* Wv = (const float*)d_in[6];
  const float* bv = (const float*)d_in[7];
  const float* Wo = (const float*)d_in[8];
  float* out = (float*)d_out;

  float* w = (float*)d_ws;
  const size_t QSZ = (size_t)BB * HH * SS * DD;         // 8388608
  const size_t KSZ = (size_t)BB * HKVV * SS * DD;       // 2097152
  const size_t TSZ = (size_t)BB * HKVV * NCH * DD * DD; // 4194304
  float* qbuf = w; w += QSZ;
  float* olin = w; w += QSZ;             // hosts hs_bf before passC
  short* sqb  = (short*)w; w += QSZ / 2; // hosts wq_bf before prep_q
  short* skb  = (short*)w; w += KSZ / 2; // hosts wk_bf before prep_k
  short* vb   = (short*)w; w += KSZ / 2; // hosts wv_bf before v-cast
  float* kbuf = w; w += KSZ;
  float* vbuf = w; w += KSZ;
  float* gbuf = w; w += KSZ;
  float* Gc   = w; w += KSZ;
  float* Tc   = w; w += TSZ;             // hosts obf after passB
  short* hT   = (short*)w; w += TSZ / 2;
  float* ct   = w; w += (size_t)SS * 64;
  float* st   = w; w += (size_t)SS * 64;
  short* wo_bf = (short*)w; w += (size_t)HIDN * HIDN / 2;

  short* hs_bf = (short*)olin;
  short* wq_bf = sqb;
  short* wk_bf = skb;
  short* wv_bf = vb;
  short* obf   = (short*)Tc;

  dim3 blk(256);
  const int M = BB * SS; // 4096

  cast_bf16_k<<<dim3(8192), blk, 0, stream>>>(hs, hs_bf, (int)(QSZ / 4));
  cast_bf16_k<<<dim3(4096), blk, 0, stream>>>(Wq, wq_bf, 4194304 / 4);
  cast_bf16_k<<<dim3(1024), blk, 0, stream>>>(Wk, wk_bf, 1048576 / 4);
  cast_bf16_k<<<dim3(1024), blk, 0, stream>>>(Wv, wv_bf, 1048576 / 4);
  cast_bf16_k<<<dim3(4096), blk, 0, stream>>>(Wo, wo_bf, 4194304 / 4);

  mfma_gemm_bt<<<dim3(HIDN / 128, M / 128), blk, 0, stream>>>(hs_bf, wq_bf, bq, qbuf, M, HH * DD, HIDN, 1, HH);
  mfma_gemm_bt<<<dim3((HKVV * DD) / 128, M / 128), blk, 0, stream>>>(hs_bf, wk_bf, bk, kbuf, M, HKVV * DD, HIDN, 1, HKVV);
  mfma_gemm_bt<<<dim3((HKVV * DD) / 128, M / 128), blk, 0, stream>>>(hs_bf, wv_bf, bv, vbuf, M, HKVV * DD, HIDN, 1, HKVV);

  // v -> bf16 (overwrites wv_bf, dead after V GEMM)
  cast_bf16_k<<<dim3((unsigned)(KSZ / 4 / 256)), blk, 0, stream>>>(vbuf, vb, (int)(KSZ / 4));

  rope_tab_k<<<dim3((SS * 64) / 256), blk, 0, stream>>>(pos, ct, st);
  prep_q_k<<<dim3(BB * HH * SS / 4), blk, 0, stream>>>(qbuf, sqb, ct, st);
  prep_k_k<<<dim3(BB * HKVV * SS / 4), blk, 0, stream>>>(kbuf, skb, gbuf, ct, st);

  gla_passA_k<<<dim3(BB * HKVV * NCH), blk, 0, stream>>>(kbuf, vbuf, gbuf, Gc, Tc);
  gla_passB_k<<<dim3(BB * HKVV * DD * DD / 256), blk, 0, stream>>>(Tc, Gc, hT);
  gla_passC_k<<<dim3(BB * HH * NCH), blk, 0, stream>>>(qbuf, kbuf, vbuf, Gc, hT, olin);

  win_attn_k<<<dim3(BB * HH * NBLK), blk, 0, stream>>>(sqb, skb, vb, olin, obf);

  mfma_gemm_bt<<<dim3(HIDN / 128, M / 128), blk, 0, stream>>>(obf, wo_bf, nullptr, out, M, HIDN, HIDN, 0, 0);
}

// Round 4
// 258.134 us; speedup vs baseline: 8.9732x; 1.3891x over previous
//
#include <hip/hip_runtime.h>
#include <hip/hip_bf16.h>
#include <math.h>

#define BB   2
#define SS   2048
#define HIDN 2048
#define HH   16
#define HKVV 4
#define DD   128
#define NCH  32   // S/CHUNK
#define CHK  64
#define NBLK 32   // S/WIN

typedef __attribute__((ext_vector_type(8))) short bf16x8;
typedef __attribute__((ext_vector_type(4))) float f32x4;

__device__ __forceinline__ short f2bf(float x)
{
  __hip_bfloat16 h = __float2bfloat16(x);
  return *(short*)&h;
}

__device__ __forceinline__ uint packbf(float a, float b)
{
  return (uint)(ushort)f2bf(a) | ((uint)(ushort)f2bf(b) << 16);
}

__device__ __forceinline__ void gld_lds16(const short* g, short* lds)
{
  __builtin_amdgcn_global_load_lds(
      (const __attribute__((address_space(1))) void*)g,
      (__attribute__((address_space(3))) void*)lds, 16, 0, 0);
}

// swizzled LDS helpers: byte ^= ((row&7)<<4) within each 8-row stripe
__device__ __forceinline__ bf16x8 ldsA(const short* base, int row, int rs, int ks)
{
  int byte = (row * rs + ks) * 2;
  byte ^= ((row & 7) << 4);
  __builtin_assume((byte & 15) == 0);
  return *(const bf16x8*)((const char*)base + byte);
}
__device__ __forceinline__ void lds_w32_swz(short* base, int row, int rs, int ks, uint v)
{
  int byte = (row * rs + ks) * 2;
  byte ^= ((row & 7) << 4);
  *(uint*)((char*)base + byte) = v;
}
__device__ __forceinline__ void lds_w16_swz(short* base, int row, int rs, int ks, short v)
{
  int byte = (row * rs + ks) * 2;
  byte ^= ((row & 7) << 4);
  *(short*)((char*)base + byte) = v;
}

// ---------------- fp32 -> bf16 cast (vectorized) --------------------------
__global__ __launch_bounds__(256) void cast_bf16_k(const float* __restrict__ in,
    short* __restrict__ out, int n4)
{
  int i = blockIdx.x * 256 + threadIdx.x;
  if (i >= n4) return;
  const float4 v = ((const float4*)in)[i];
  short4 o;
  o.x = f2bf(v.x); o.y = f2bf(v.y); o.z = f2bf(v.z); o.w = f2bf(v.w);
  ((short4*)out)[i] = o;
}

// ---------------- fused QKV GEMM: [q|k|v] = hs @ Wqkv^T + b ---------------
// A: 4096x2048 bf16. Bt: 3072x2048 bf16 (rows 0..2047 Wq, ..2559 Wk, ..3071 Wv)
// Stores f32 head-layout q/k/v; for v also bf16 copy. 1D grid 768, XCD-swizzled.
__global__ __launch_bounds__(256) void qkv_gemm_k(
    const short* __restrict__ A, const short* __restrict__ Bt,
    const float* __restrict__ bq, const float* __restrict__ bk,
    const float* __restrict__ bv, float* __restrict__ qо_unused,
    float* __restrict__ qbuf, float* __restrict__ kbuf, float* __restrict__ vbuf,
    short* __restrict__ vb)
{
  const int K = HIDN, GX = 24;        // N/128 tiles
  __shared__ short As[128 * 32];
  __shared__ short Bs[128 * 32];
  int orig = blockIdx.x;
  int wg = ((orig & 7) * 96) + (orig >> 3);  // nwg=768, q0=96, bijective
  int bm = (wg / GX) * 128, bn = (wg % GX) * 128;
  int tid = threadIdx.x;
  int wave = tid >> 6, lane = tid & 63;
  int wr = wave >> 1, wc = wave & 1;

  f32x4 acc[4][4];
  #pragma unroll
  for (int m = 0; m < 4; m++)
    #pragma unroll
    for (int n = 0; n < 4; n++) acc[m][n] = (f32x4){0.f, 0.f, 0.f, 0.f};

  int srow = lane >> 2;
  int scol = (lane & 3) * 8;
  const short* Abase = A + (size_t)bm * K;
  const short* Bbase = Bt + (size_t)bn * K;

  for (int k0 = 0; k0 < K; k0 += 32) {
    #pragma unroll
    for (int t = wave; t < 8; t += 4) {
      gld_lds16(Abase + (size_t)(t * 16 + srow) * K + k0 + scol, &As[t * 512]);
      gld_lds16(Bbase + (size_t)(t * 16 + srow) * K + k0 + scol, &Bs[t * 512]);
    }
    __syncthreads();
    int koff = (lane >> 4) * 8;
    int ar = wr * 64 + (lane & 15);
    int br = wc * 64 + (lane & 15);
    bf16x8 af[4], bfr[4];
    #pragma unroll
    for (int m = 0; m < 4; m++) af[m] = *(const bf16x8*)&As[(ar + m * 16) * 32 + koff];
    #pragma unroll
    for (int n = 0; n < 4; n++) bfr[n] = *(const bf16x8*)&Bs[(br + n * 16) * 32 + koff];
    #pragma unroll
    for (int m = 0; m < 4; m++)
      #pragma unroll
      for (int n = 0; n < 4; n++)
        acc[m][n] = __builtin_amdgcn_mfma_f32_16x16x32_bf16(af[m], bfr[n], acc[m][n], 0, 0, 0);
    __syncthreads();
  }

  int crow0 = wr * 64 + (lane >> 4) * 4;
  int ccol0 = wc * 64 + (lane & 15);
  // tile-uniform projection select
  int proj = (bn < 2048) ? 0 : ((bn < 2560) ? 1 : 2);
  #pragma unroll
  for (int m = 0; m < 4; m++) {
    #pragma unroll
    for (int n = 0; n < 4; n++) {
      int nn = bn + ccol0 + n * 16;
      float bvl;
      if (proj == 0) bvl = bq[nn];
      else if (proj == 1) bvl = bk[nn - 2048];
      else bvl = bv[nn - 2560];
      #pragma unroll
      for (int r = 0; r < 4; r++) {
        int mm = bm + crow0 + m * 16 + r;
        int b = mm >> 11, s = mm & 2047;
        float val = acc[m][n][r] + bvl;
        if (proj == 0) {
          int hh = nn >> 7, d = nn & 127;
          qbuf[(size_t)((b * HH + hh) * SS + s) * DD + d] = val;
        } else if (proj == 1) {
          int nq = nn - 2048, hh = nq >> 7, d = nq & 127;
          kbuf[(size_t)((b * HKVV + hh) * SS + s) * DD + d] = val;
        } else {
          int nq = nn - 2560, hh = nq >> 7, d = nq & 127;
          size_t idx = (size_t)((b * HKVV + hh) * SS + s) * DD + d;
          vbuf[idx] = val;
          vb[idx] = f2bf(val);
        }
      }
    }
  }
}

// ---------------- bf16 MFMA GEMM (plain store), 1D grid XCD-swizzled ------
__global__ __launch_bounds__(256) void mfma_gemm_bt(
    const short* __restrict__ A, const short* __restrict__ Bt,
    float* __restrict__ C, int M, int N, int K, int gx, int q0)
{
  __shared__ short As[128 * 32];
  __shared__ short Bs[128 * 32];
  int orig = blockIdx.x;
  int wg = ((orig & 7) * q0) + (orig >> 3);
  int bm = (wg / gx) * 128, bn = (wg % gx) * 128;
  int tid = threadIdx.x;
  int wave = tid >> 6, lane = tid & 63;
  int wr = wave >> 1, wc = wave & 1;

  f32x4 acc[4][4];
  #pragma unroll
  for (int m = 0; m < 4; m++)
    #pragma unroll
    for (int n = 0; n < 4; n++) acc[m][n] = (f32x4){0.f, 0.f, 0.f, 0.f};

  int srow = lane >> 2;
  int scol = (lane & 3) * 8;
  const short* Abase = A + (size_t)bm * K;
  const short* Bbase = Bt + (size_t)bn * K;

  for (int k0 = 0; k0 < K; k0 += 32) {
    #pragma unroll
    for (int t = wave; t < 8; t += 4) {
      gld_lds16(Abase + (size_t)(t * 16 + srow) * K + k0 + scol, &As[t * 512]);
      gld_lds16(Bbase + (size_t)(t * 16 + srow) * K + k0 + scol, &Bs[t * 512]);
    }
    __syncthreads();
    int koff = (lane >> 4) * 8;
    int ar = wr * 64 + (lane & 15);
    int br = wc * 64 + (lane & 15);
    bf16x8 af[4], bfr[4];
    #pragma unroll
    for (int m = 0; m < 4; m++) af[m] = *(const bf16x8*)&As[(ar + m * 16) * 32 + koff];
    #pragma unroll
    for (int n = 0; n < 4; n++) bfr[n] = *(const bf16x8*)&Bs[(br + n * 16) * 32 + koff];
    #pragma unroll
    for (int m = 0; m < 4; m++)
      #pragma unroll
      for (int n = 0; n < 4; n++)
        acc[m][n] = __builtin_amdgcn_mfma_f32_16x16x32_bf16(af[m], bfr[n], acc[m][n], 0, 0, 0);
    __syncthreads();
  }

  int crow0 = wr * 64 + (lane >> 4) * 4;
  int ccol0 = wc * 64 + (lane & 15);
  #pragma unroll
  for (int m = 0; m < 4; m++)
    #pragma unroll
    for (int n = 0; n < 4; n++) {
      int nn = bn + ccol0 + n * 16;
      #pragma unroll
      for (int r = 0; r < 4; r++) {
        int mm = bm + crow0 + m * 16 + r;
        C[(size_t)mm * N + nn] = acc[m][n][r];
      }
    }
}

// ---------------- RoPE cos/sin table: (S x 64) ----------------------------
__global__ void rope_tab_k(const int* __restrict__ pos, float* __restrict__ ct,
                           float* __restrict__ st)
{
  int id = blockIdx.x * 256 + threadIdx.x;
  if (id >= SS * 64) return;
  int s = id >> 6, i = id & 63;
  double inv = pow(1.0e6, -(double)(2 * i) / 128.0);
  double ang = (double)pos[s] * inv;
  ct[id] = (float)cos(ang);
  st[id] = (float)sin(ang);
}

__device__ __forceinline__ float logsigf(float x)
{
  return (x >= 0.f) ? -log1pf(expf(-x)) : x - log1pf(expf(x));
}

// ---------------- prep q: softmax (in place) + rope -> sqb (bf16) ---------
__global__ __launch_bounds__(256) void prep_q_k(float* __restrict__ q,
    short* __restrict__ sqb, const float* __restrict__ ct, const float* __restrict__ st)
{
  int row = blockIdx.x * 4 + (threadIdx.x >> 6);
  int lane = threadIdx.x & 63;
  size_t base = (size_t)row * 128;
  int s = row & (SS - 1);
  float x0 = q[base + lane], x1 = q[base + 64 + lane];
  float m = fmaxf(x0, x1);
  for (int o = 32; o > 0; o >>= 1) m = fmaxf(m, __shfl_xor(m, o));
  float e0 = expf(x0 - m), e1 = expf(x1 - m);
  float sum = e0 + e1;
  for (int o = 32; o > 0; o >>= 1) sum += __shfl_xor(sum, o);
  float inv = 1.0f / sum;
  q[base + lane] = e0 * inv;
  q[base + 64 + lane] = e1 * inv;
  float c = ct[s * 64 + lane], sn = st[s * 64 + lane];
  sqb[base + lane]      = f2bf(x0 * c - x1 * sn);
  sqb[base + 64 + lane] = f2bf(x1 * c + x0 * sn);
}

// ---------------- prep k: softmax + gate + rope -> skb (bf16) -------------
__global__ __launch_bounds__(256) void prep_k_k(float* __restrict__ k,
    short* __restrict__ skb, float* __restrict__ g,
    const float* __restrict__ ct, const float* __restrict__ st)
{
  int row = blockIdx.x * 4 + (threadIdx.x >> 6);
  int lane = threadIdx.x & 63;
  size_t base = (size_t)row * 128;
  int s = row & (SS - 1);
  float x0 = k[base + lane], x1 = k[base + 64 + lane];
  float m = fmaxf(x0, x1);
  for (int o = 32; o > 0; o >>= 1) m = fmaxf(m, __shfl_xor(m, o));
  float e0 = expf(x0 - m), e1 = expf(x1 - m);
  float sum = e0 + e1;
  for (int o = 32; o > 0; o >>= 1) sum += __shfl_xor(sum, o);
  float inv = 1.0f / sum;
  k[base + lane] = e0 * inv;
  k[base + 64 + lane] = e1 * inv;
  g[base + lane]      = logsigf(x0) * (1.0f / 16.0f);
  g[base + 64 + lane] = logsigf(x1) * (1.0f / 16.0f);
  float c = ct[s * 64 + lane], sn = st[s * 64 + lane];
  skb[base + lane]      = f2bf(x0 * c - x1 * sn);
  skb[base + 64 + lane] = f2bf(x1 * c + x0 * sn);
}

// ---------------- GLA pass A (MFMA): Gc cumsum + Tc = Kg^T V (as [v][k]) --
__global__ __launch_bounds__(256) void gla_passA_k(
    const float* __restrict__ ks, const float* __restrict__ v,
    const float* __restrict__ g, float* __restrict__ Gc, float* __restrict__ Tc)
{
  int bx = blockIdx.x;             // bkvh*NCH + c
  int c = bx & 31;
  int bkvh = bx >> 5;
  __shared__ float Gs[64][128];    // 32 KB
  __shared__ short KgT[128 * 64];  // swizzled bf16, [k][j]
  __shared__ short VT[128 * 64];   // swizzled bf16, [v][j]
  size_t rowbase = ((size_t)bkvh * SS + c * 64) * 128;
  int tid = threadIdx.x, w = tid >> 6, l = tid & 63, gi = l >> 4;

  {
    int j = tid >> 1, d0 = (tid & 1) * 64;
    const float4* g4 = (const float4*)(g + rowbase + j * 128 + d0);
    float4* gs4 = (float4*)&Gs[j][d0];
    #pragma unroll
    for (int u = 0; u < 16; u++) gs4[u] = g4[u];
  }
  __syncthreads();
  if (tid < 128) {
    float run = 0.f;
    for (int j = 0; j < 64; j++) { run += Gs[j][tid]; Gs[j][tid] = run; }
  }
  __syncthreads();
  {
    int j = tid >> 2, d0 = (tid & 3) * 32;
    const float4* k4 = (const float4*)(ks + rowbase + j * 128 + d0);
    const float4* v4 = (const float4*)(v + rowbase + j * 128 + d0);
    float4* gc4 = (float4*)(Gc + rowbase + j * 128 + d0);
    #pragma unroll
    for (int u = 0; u < 8; u++) {
      float4 kv = k4[u], vv = v4[u];
      int d = d0 + 4 * u;
      float g0 = Gs[j][d], g1 = Gs[j][d + 1], g2 = Gs[j][d + 2], g3 = Gs[j][d + 3];
      gc4[u] = make_float4(g0, g1, g2, g3);
      float kg0 = kv.x * __expf(Gs[63][d]     - g0);
      float kg1 = kv.y * __expf(Gs[63][d + 1] - g1);
      float kg2 = kv.z * __expf(Gs[63][d + 2] - g2);
      float kg3 = kv.w * __expf(Gs[63][d + 3] - g3);
      lds_w16_swz(KgT, d + 0, 64, j, f2bf(kg0));
      lds_w16_swz(KgT, d + 1, 64, j, f2bf(kg1));
      lds_w16_swz(KgT, d + 2, 64, j, f2bf(kg2));
      lds_w16_swz(KgT, d + 3, 64, j, f2bf(kg3));
      lds_w16_swz(VT, d + 0, 64, j, f2bf(vv.x));
      lds_w16_swz(VT, d + 1, 64, j, f2bf(vv.y));
      lds_w16_swz(VT, d + 2, 64, j, f2bf(vv.z));
      lds_w16_swz(VT, d + 3, 64, j, f2bf(vv.w));
    }
  }
  __syncthreads();
  // Tc[vv][kk] = sum_j V[j][vv] * Kg[j][kk]; wave w owns vv in [32w,32w+32)
  f32x4 acc[2][8];
  #pragma unroll
  for (int m = 0; m < 2; m++)
    #pragma unroll
    for (int n = 0; n < 8; n++) acc[m][n] = (f32x4){0.f, 0.f, 0.f, 0.f};
  #pragma unroll
  for (int k0i = 0; k0i < 2; k0i++) {
    int k0 = k0i * 32 + gi * 8;
    bf16x8 af[2];
    #pragma unroll
    for (int m = 0; m < 2; m++) af[m] = ldsA(VT, 32 * w + 16 * m + (l & 15), 64, k0);
    #pragma unroll
    for (int n = 0; n < 8; n++) {
      bf16x8 bfr = ldsA(KgT, 16 * n + (l & 15), 64, k0);
      #pragma unroll
      for (int m = 0; m < 2; m++)
        acc[m][n] = __builtin_amdgcn_mfma_f32_16x16x32_bf16(af[m], bfr, acc[m][n], 0, 0, 0);
    }
  }
  size_t tbase = (size_t)bx * 16384;
  #pragma unroll
  for (int m = 0; m < 2; m++)
    #pragma unroll
    for (int n = 0; n < 8; n++)
      #pragma unroll
      for (int r = 0; r < 4; r++) {
        int vv = 32 * w + 16 * m + 4 * gi + r;
        int kk = 16 * n + (l & 15);
        Tc[tbase + (size_t)vv * 128 + kk] = acc[m][n][r];
      }
}

// ---------------- GLA pass B: scan; Tc is [v][k]; writes hT[v][k] bf16 ----
__global__ __launch_bounds__(256) void gla_passB_k(
    const float* __restrict__ Tc, const float* __restrict__ Gc,
    short* __restrict__ hT)
{
  int id = blockIdx.x * 256 + threadIdx.x; // (bkvh, v, k)
  int bkvh = id >> 14;
  int vk = id & 16383;
  int kk = vk & 127;
  float h = 0.f;
  for (int c = 0; c < NCH; ++c) {
    size_t cb = ((size_t)(bkvh * NCH + c) << 14);
    hT[cb + vk] = f2bf(h);
    float gl = Gc[((size_t)bkvh * SS + c * 64 + 63) * 128 + kk];
    h = h * __expf(gl) + Tc[cb + vk];
  }
}

// ---------------- GLA pass C (MFMA): o = tril(qe keT) v + qe h ------------
__global__ __launch_bounds__(256) void gla_passC_k(
    const float* __restrict__ qs, const float* __restrict__ ks,
    const float* __restrict__ v, const float* __restrict__ Gc,
    const short* __restrict__ hT, float* __restrict__ olin)
{
  int bx = blockIdx.x;            // (b*H+h)*NCH + c
  int c = bx & 31;
  int bh = bx >> 5;
  int b = bh >> 4, hq = bh & 15;
  int bkvh = b * HKVV + (hq >> 2);
  __shared__ short QeB[64 * 128];
  __shared__ short KeB[64 * 128];  // first 4096 reused as AmB after B1
  __shared__ short VtB[128 * 64];
  int tid = threadIdx.x, w = tid >> 6, l = tid & 63, g = l >> 4;
  size_t qrow = ((size_t)bh * SS + c * 64) * 128;
  size_t krow = ((size_t)bkvh * SS + c * 64) * 128;

  const short* hTb = hT + (((size_t)(bkvh * NCH + c)) << 14);
  bf16x8 hB[4][2];
  #pragma unroll
  for (int k0i = 0; k0i < 4; k0i++)
    #pragma unroll
    for (int nt = 0; nt < 2; nt++)
      hB[k0i][nt] = *(const bf16x8*)(hTb + (size_t)(32 * w + 16 * nt + (l & 15)) * 128 + k0i * 32 + g * 8);

  {
    int j = tid >> 2, d0 = (tid & 3) * 32;
    const float4* q4 = (const float4*)(qs + qrow + j * 128 + d0);
    const float4* k4 = (const float4*)(ks + krow + j * 128 + d0);
    const float4* g4 = (const float4*)(Gc + krow + j * 128 + d0);
    const float4* v4 = (const float4*)(v + krow + j * 128 + d0);
    #pragma unroll
    for (int u = 0; u < 8; u++) {
      float4 qv = q4[u], kv = k4[u], gv = g4[u], vv = v4[u];
      float e0 = __expf(gv.x), e1 = __expf(gv.y), e2 = __expf(gv.z), e3 = __expf(gv.w);
      lds_w32_swz(QeB, j, 128, d0 + 4 * u,     packbf(qv.x * e0, qv.y * e1));
      lds_w32_swz(QeB, j, 128, d0 + 4 * u + 2, packbf(qv.z * e2, qv.w * e3));
      lds_w32_swz(KeB, j, 128, d0 + 4 * u,     packbf(kv.x / e0, kv.y / e1));
      lds_w32_swz(KeB, j, 128, d0 + 4 * u + 2, packbf(kv.z / e2, kv.w / e3));
      lds_w16_swz(VtB, d0 + 4 * u + 0, 64, j, f2bf(vv.x));
      lds_w16_swz(VtB, d0 + 4 * u + 1, 64, j, f2bf(vv.y));
      lds_w16_swz(VtB, d0 + 4 * u + 2, 64, j, f2bf(vv.z));
      lds_w16_swz(VtB, d0 + 4 * u + 3, 64, j, f2bf(vv.w));
    }
  }
  __syncthreads(); // B0

  f32x4 acc1[4];
  #pragma unroll
  for (int m = 0; m < 4; m++) acc1[m] = (f32x4){0.f, 0.f, 0.f, 0.f};
  #pragma unroll
  for (int k0i = 0; k0i < 4; k0i++) {
    int k0 = k0i * 32 + g * 8;
    bf16x8 bk = ldsA(KeB, 16 * w + (l & 15), 128, k0);
    #pragma unroll
    for (int m = 0; m < 4; m++) {
      bf16x8 af = ldsA(QeB, 16 * m + (l & 15), 128, k0);
      acc1[m] = __builtin_amdgcn_mfma_f32_16x16x32_bf16(af, bk, acc1[m], 0, 0, 0);
    }
  }
  __syncthreads(); // B1
  short* AmB = KeB;
  #pragma unroll
  for (int m = 0; m < 4; m++)
    #pragma unroll
    for (int r = 0; r < 4; r++) {
      int i = 16 * m + 4 * g + r;
      int j = 16 * w + (l & 15);
      float val = (j <= i) ? acc1[m][r] : 0.f;
      lds_w16_swz(AmB, i, 64, j, f2bf(val));
    }
  __syncthreads(); // B2

  f32x4 acc[4][2];
  #pragma unroll
  for (int m = 0; m < 4; m++)
    #pragma unroll
    for (int nt = 0; nt < 2; nt++) acc[m][nt] = (f32x4){0.f, 0.f, 0.f, 0.f};
  #pragma unroll
  for (int k0i = 0; k0i < 2; k0i++) {
    int k0 = k0i * 32 + g * 8;
    bf16x8 bfr[2];
    #pragma unroll
    for (int nt = 0; nt < 2; nt++) bfr[nt] = ldsA(VtB, 32 * w + 16 * nt + (l & 15), 64, k0);
    #pragma unroll
    for (int m = 0; m < 4; m++) {
      bf16x8 af = ldsA(AmB, 16 * m + (l & 15), 64, k0);
      #pragma unroll
      for (int nt = 0; nt < 2; nt++)
        acc[m][nt] = __builtin_amdgcn_mfma_f32_16x16x32_bf16(af, bfr[nt], acc[m][nt], 0, 0, 0);
    }
  }
  #pragma unroll
  for (int k0i = 0; k0i < 4; k0i++) {
    int k0 = k0i * 32 + g * 8;
    #pragma unroll
    for (int m = 0; m < 4; m++) {
      bf16x8 af = ldsA(QeB, 16 * m + (l & 15), 128, k0);
      #pragma unroll
      for (int nt = 0; nt < 2; nt++)
        acc[m][nt] = __builtin_amdgcn_mfma_f32_16x16x32_bf16(af, hB[k0i][nt], acc[m][nt], 0, 0, 0);
    }
  }
  #pragma unroll
  for (int m = 0; m < 4; m++)
    #pragma unroll
    for (int nt = 0; nt < 2; nt++)
      #pragma unroll
      for (int r = 0; r < 4; r++) {
        int i = 16 * m + 4 * g + r, d = 32 * w + 16 * nt + (l & 15);
        olin[qrow + (size_t)i * 128 + d] = acc[m][nt][r];
      }
}

// ---------------- windowed attention (MFMA) + mix -> bf16 (B,S,H*D) -------
__global__ __launch_bounds__(256) void win_attn_k(
    const short* __restrict__ sqb, const short* __restrict__ skb,
    const short* __restrict__ vb, const float* __restrict__ olin,
    short* __restrict__ obf)
{
  int bx = blockIdx.x;            // (b*H+h)*NBLK + n
  int n = bx & 31;
  int bh = bx >> 5;
  int b = bh >> 4, hq = bh & 15;
  int bkvh = b * HKVV + (hq >> 2);
  __shared__ short Qs[64 * 128];   // then P (bf16)
  __shared__ short Ks[128 * 128];  // then V^T (bf16)
  __shared__ float wred[2][4][64];
  int tid = threadIdx.x, w = tid >> 6, l = tid & 63, g = l >> 4;
  const short* qg = sqb + ((size_t)bh * SS + n * 64) * 128;
  const short* kg = skb + (size_t)bkvh * SS * 128 + (ptrdiff_t)(n - 1) * 64 * 128;

  for (int c0 = w * 64; c0 < 1024; c0 += 256) {
    int cc = c0 + l, row = cc >> 4;
    int gb = (cc << 4) ^ ((row & 7) << 4);
    gld_lds16((const short*)((const char*)qg + gb), Qs + c0 * 8);
  }
  for (int c0 = w * 64; c0 < 2048; c0 += 256) {
    int cc = c0 + l, row = cc >> 4;
    int gb = (cc << 4) ^ ((row & 7) << 4);
    gld_lds16((const short*)((const char*)kg + gb), Ks + c0 * 8);
  }
  __syncthreads(); // B0

  f32x4 acc[4][2];
  #pragma unroll
  for (int m = 0; m < 4; m++)
    #pragma unroll
    for (int nt = 0; nt < 2; nt++) acc[m][nt] = (f32x4){0.f, 0.f, 0.f, 0.f};
  #pragma unroll
  for (int k0i = 0; k0i < 4; k0i++) {
    int k0 = k0i * 32 + g * 8;
    bf16x8 bfr[2];
    #pragma unroll
    for (int nt = 0; nt < 2; nt++) bfr[nt] = ldsA(Ks, 32 * w + 16 * nt + (l & 15), 128, k0);
    #pragma unroll
    for (int m = 0; m < 4; m++) {
      bf16x8 af = ldsA(Qs, 16 * m + (l & 15), 128, k0);
      #pragma unroll
      for (int nt = 0; nt < 2; nt++)
        acc[m][nt] = __builtin_amdgcn_mfma_f32_16x16x32_bf16(af, bfr[nt], acc[m][nt], 0, 0, 0);
    }
  }

  const float scale = 0.08838834764831845f;
  float mx[4][4];
  #pragma unroll
  for (int m = 0; m < 4; m++)
    #pragma unroll
    for (int r = 0; r < 4; r++) mx[m][r] = -1e30f;
  #pragma unroll
  for (int m = 0; m < 4; m++)
    #pragma unroll
    for (int nt = 0; nt < 2; nt++)
      #pragma unroll
      for (int r = 0; r < 4; r++) {
        int i = 16 * m + 4 * g + r;
        int j = 32 * w + 16 * nt + (l & 15);
        int kp = (n - 1) * 64 + j;
        bool valid = (j >= i) && (j <= i + 64) && (kp >= 0);
        float sc = valid ? acc[m][nt][r] * scale : -1e30f;
        acc[m][nt][r] = sc;
        mx[m][r] = fmaxf(mx[m][r], sc);
      }
  #pragma unroll
  for (int m = 0; m < 4; m++)
    #pragma unroll
    for (int r = 0; r < 4; r++) {
      #pragma unroll
      for (int msk = 1; msk < 16; msk <<= 1) mx[m][r] = fmaxf(mx[m][r], __shfl_xor(mx[m][r], msk));
    }
  if ((l & 15) == 0)
    #pragma unroll
    for (int m = 0; m < 4; m++)
      #pragma unroll
      for (int r = 0; r < 4; r++) wred[0][w][16 * m + 4 * g + r] = mx[m][r];
  __syncthreads(); // B1

  float mrow[4][4], sm[4][4];
  #pragma unroll
  for (int m = 0; m < 4; m++)
    #pragma unroll
    for (int r = 0; r < 4; r++) {
      int i = 16 * m + 4 * g + r;
      mrow[m][r] = fmaxf(fmaxf(wred[0][0][i], wred[0][1][i]), fmaxf(wred[0][2][i], wred[0][3][i]));
      sm[m][r] = 0.f;
    }
  #pragma unroll
  for (int m = 0; m < 4; m++)
    #pragma unroll
    for (int nt = 0; nt < 2; nt++)
      #pragma unroll
      for (int r = 0; r < 4; r++) {
        float p = __expf(acc[m][nt][r] - mrow[m][r]);
        acc[m][nt][r] = p;
        sm[m][r] += p;
      }
  #pragma unroll
  for (int m = 0; m < 4; m++)
    #pragma unroll
    for (int r = 0; r < 4; r++) {
      #pragma unroll
      for (int msk = 1; msk < 16; msk <<= 1) sm[m][r] += __shfl_xor(sm[m][r], msk);
    }
  if ((l & 15) == 0)
    #pragma unroll
    for (int m = 0; m < 4; m++)
      #pragma unroll
      for (int r = 0; r < 4; r++) wred[1][w][16 * m + 4 * g + r] = sm[m][r];
  __syncthreads(); // B2

  #pragma unroll
  for (int m = 0; m < 4; m++)
    #pragma unroll
    for (int r = 0; r < 4; r++) {
      int i = 16 * m + 4 * g + r;
      float s = wred[1][0][i] + wred[1][1][i] + wred[1][2][i] + wred[1][3][i];
      float inv = 1.0f / s;
      #pragma unroll
      for (int nt = 0; nt < 2; nt++) {
        int j = 32 * w + 16 * nt + (l & 15);
        lds_w16_swz(Qs, i, 128, j, f2bf(acc[m][nt][r] * inv));
      }
    }
  {
    int j = tid >> 1, dh = (tid & 1) * 64;
    int kp = (n - 1) * 64 + j;
    const short* vrow = vb + ((size_t)bkvh * SS + kp) * 128 + dh;
    #pragma unroll
    for (int u = 0; u < 8; u++) {
      bf16x8 vv;
      if (kp >= 0) vv = *(const bf16x8*)(vrow + u * 8);
      else vv = (bf16x8){0, 0, 0, 0, 0, 0, 0, 0};
      #pragma unroll
      for (int i2 = 0; i2 < 8; i2++)
        lds_w16_swz(Ks, dh + u * 8 + i2, 128, j, vv[i2]);
    }
  }
  __syncthreads(); // B3

  f32x4 o[4][2];
  #pragma unroll
  for (int m = 0; m < 4; m++)
    #pragma unroll
    for (int nt = 0; nt < 2; nt++) o[m][nt] = (f32x4){0.f, 0.f, 0.f, 0.f};
  #pragma unroll
  for (int k0i = 0; k0i < 4; k0i++) {
    int k0 = k0i * 32 + g * 8;
    bf16x8 bfr[2];
    #pragma unroll
    for (int nt = 0; nt < 2; nt++) bfr[nt] = ldsA(Ks, 32 * w + 16 * nt + (l & 15), 128, k0);
    #pragma unroll
    for (int m = 0; m < 4; m++) {
      bf16x8 af = ldsA(Qs, 16 * m + (l & 15), 128, k0);
      #pragma unroll
      for (int nt = 0; nt < 2; nt++)
        o[m][nt] = __builtin_amdgcn_mfma_f32_16x16x32_bf16(af, bfr[nt], o[m][nt], 0, 0, 0);
    }
  }
  #pragma unroll
  for (int m = 0; m < 4; m++)
    #pragma unroll
    for (int nt = 0; nt < 2; nt++)
      #pragma unroll
      for (int r = 0; r < 4; r++) {
        int i = 16 * m + 4 * g + r, d = 32 * w + 16 * nt + (l & 15);
        float val = 0.5f * o[m][nt][r] + 0.5f * olin[((size_t)bh * SS + n * 64 + i) * 128 + d];
        obf[((size_t)(b * SS + n * 64 + i)) * HIDN + hq * 128 + d] = f2bf(val);
      }
}

// --------------------------------------------------------------------------
extern "C" void kernel_launch(void* const* d_in, const int* in_sizes, int n_in,
                              void* d_out, int out_size, void* d_ws, size_t ws_size,
                              hipStream_t stream)
{
  const float* hs = (const float*)d_in[0];
  const int*  pos = (const int*)d_in[1];
  const float* Wq = (const float*)d_in[2];
  const float* bq = (const float*)d_in[3];
  const float* Wk = (const float*)d_in[4];
  const float* bk = (const float*)d_in[5];
  const float* Wv = (const float*)d_in[6];
  const float* bv = (const float*)d_in[7];
  const float* Wo = (const float*)d_in[8];
  float* out = (float*)d_out;

  float* w = (float*)d_ws;
  const size_t QSZ = (size_t)BB * HH * SS * DD;         // 8388608
  const size_t KSZ = (size_t)BB * HKVV * SS * DD;       // 2097152
  const size_t TSZ = (size_t)BB * HKVV * NCH * DD * DD; // 4194304
  float* qbuf = w; w += QSZ;
  float* olin = w; w += QSZ;             // hosts hs_bf before passC
  short* sqb  = (short*)w; w += QSZ / 2;
  short* skb  = (short*)w; w += KSZ / 2;
  short* vb   = (short*)w; w += KSZ / 2;
  float* kbuf = w; w += KSZ;
  float* vbuf = w; w += KSZ;
  float* gbuf = w; w += KSZ;
  float* Gc   = w; w += KSZ;
  float* Tc   = w; w += TSZ;             // hosts obf after passB
  short* hT   = (short*)w; w += TSZ / 2;
  float* ct   = w; w += (size_t)SS * 64;
  float* st   = w; w += (size_t)SS * 64;
  short* wo_bf = (short*)w; w += (size_t)HIDN * HIDN / 2;
  short* wqkv_bf = (short*)w; w += (size_t)3072 * HIDN / 2;

  short* hs_bf = (short*)olin;
  short* obf   = (short*)Tc;

  dim3 blk(256);
  const int M = BB * SS; // 4096

  cast_bf16_k<<<dim3(8192), blk, 0, stream>>>(hs, hs_bf, (int)(QSZ / 4));
  cast_bf16_k<<<dim3(4096), blk, 0, stream>>>(Wq, wqkv_bf, 4194304 / 4);
  cast_bf16_k<<<dim3(1024), blk, 0, stream>>>(Wk, wqkv_bf + 4194304, 1048576 / 4);
  cast_bf16_k<<<dim3(1024), blk, 0, stream>>>(Wv, wqkv_bf + 5242880, 1048576 / 4);
  cast_bf16_k<<<dim3(4096), blk, 0, stream>>>(Wo, wo_bf, 4194304 / 4);

  // fused QKV projection (768 blocks, XCD-swizzled)
  qkv_gemm_k<<<dim3(768), blk, 0, stream>>>(hs_bf, wqkv_bf, bq, bk, bv, nullptr,
                                            qbuf, kbuf, vbuf, vb);

  rope_tab_k<<<dim3((SS * 64) / 256), blk, 0, stream>>>(pos, ct, st);
  prep_q_k<<<dim3(BB * HH * SS / 4), blk, 0, stream>>>(qbuf, sqb, ct, st);
  prep_k_k<<<dim3(BB * HKVV * SS / 4), blk, 0, stream>>>(kbuf, skb, gbuf, ct, st);

  gla_passA_k<<<dim3(BB * HKVV * NCH), blk, 0, stream>>>(kbuf, vbuf, gbuf, Gc, Tc);
  gla_passB_k<<<dim3(BB * HKVV * DD * DD / 256), blk, 0, stream>>>(Tc, Gc, hT);
  gla_passC_k<<<dim3(BB * HH * NCH), blk, 0, stream>>>(qbuf, kbuf, vbuf, Gc, hT, olin);

  win_attn_k<<<dim3(BB * HH * NBLK), blk, 0, stream>>>(sqb, skb, vb, olin, obf);

  // out = o_mix @ Wo^T (512 blocks, XCD-swizzled)
  mfma_gemm_bt<<<dim3(512), blk, 0, stream>>>(obf, wo_bf, out, M, HIDN, HIDN, 16, 64);
}